// Round 7
// baseline (858.875 us; speedup 1.0000x reference)
//
#include <hip/hip_runtime.h>

// OrthogonalTransform via hierarchical compact-WY + MFMA application.
// out = X Q^T, Q = H_0...H_{n-1}, U = triu(weight), U[-1,-1] = 1.
// Pipeline:
//   prep_split    : UM (fp32) + UMh/UMl (bf16 hi/lo) in one pass
//   gram32/t32/wt32: parallel base-32 WY build                  [proven r6]
//   merges k=32,64: fp32 split-K ct + reduce + update           [proven r5]
//   merges k>=128 : MFMA ct (split-K partials, B pre-split) +
//                   MFMA update (A = sum of SK partials in staging)
//   trans_conv    : WT -> WTTh/WTTl (transpose + bf16 split)
//   gemm1         : A1h/l = bf16split(X UM^T)  (MFMA split-3, tri-skip, BK=64)
//   gemm2         : out = X - A1 WTT^T         (MFMA split-3, BK=64)
//
// ws layout (floats, 16M = 64 MB):
//   [0,4M)    WT                    -> A1h after trans_conv
//   [4M,8M)   UM fp32 (dead after k=64 level) -> A1l
//   [8M,12M)  ladder temporaries: Pg/Tg (base), Ct [8M,9M), Pt [9M,11M)
//             -> WTTh/WTTl after trans_conv
//   [12M,16M) UMh + UMl (written by prep_split, live through gemm1)

#define N_DIM 2048
#define NT64 32
#define NT128 16

typedef __attribute__((ext_vector_type(8))) short bf16x8;
typedef __attribute__((ext_vector_type(4))) float f32x4;
typedef unsigned short ushort_t;

__device__ __forceinline__ ushort_t f2bf_rtne(float f) {
  unsigned u = __builtin_bit_cast(unsigned, f);
  u += 0x7FFFu + ((u >> 16) & 1u);
  return (ushort_t)(u >> 16);
}
__device__ __forceinline__ float bf2f(ushort_t h) {
  return __builtin_bit_cast(float, (unsigned)h << 16);
}

// =================== prep + split ===================

__global__ __launch_bounds__(256)
void prep_split_kernel(const float* __restrict__ w, float* __restrict__ UM,
                       ushort_t* __restrict__ UMh, ushort_t* __restrict__ UMl) {
  const size_t i4 = ((size_t)blockIdx.x * 256 + threadIdx.x) * 4;
  const int j = (int)(i4 >> 11);
  const int c = (int)(i4 & (N_DIM - 1));
  const float4 v = *(const float4*)(w + i4);
  float f[4] = {v.x, v.y, v.z, v.w};
  ushort_t h[4], l[4];
#pragma unroll
  for (int q = 0; q < 4; ++q) {
    const int cc = c + q;
    float val = f[q];
    if (j == N_DIM - 1 && cc == N_DIM - 1) val = 1.0f;
    val = (cc >= j) ? val : 0.f;
    f[q] = val;
    h[q] = f2bf_rtne(val);
    l[q] = f2bf_rtne(val - bf2f(h[q]));
  }
  *(float4*)(UM + i4) = make_float4(f[0], f[1], f[2], f[3]);
  *(uint2*)(UMh + i4) = make_uint2((unsigned)h[0] | ((unsigned)h[1] << 16),
                                   (unsigned)h[2] | ((unsigned)h[3] << 16));
  *(uint2*)(UMl + i4) = make_uint2((unsigned)l[0] | ((unsigned)l[1] << 16),
                                   (unsigned)l[2] | ((unsigned)l[3] << 16));
}

// =================== base-32 WY build (proven r6) ===================

__global__ __launch_bounds__(256)
void gram32_partial(const float* __restrict__ UM, float* __restrict__ Pg) {
  const int g = blockIdx.x >> 3;
  const int s = blockIdx.x & 7;
  const int i0 = g * 32;
  const int t = threadIdx.x;
  float* dst = Pg + (size_t)blockIdx.x * 1024;
  if ((s + 1) * 256 <= i0) {
    *(float4*)(dst + t * 4) = make_float4(0.f, 0.f, 0.f, 0.f);
    return;
  }
  __shared__ float Vs[32 * 132];
  const int a2 = (t >> 4) * 2, b2 = (t & 15) * 2;
  const int r0 = t >> 3, sg = (t & 7) * 16;
  float s00 = 0.f, s01 = 0.f, s10 = 0.f, s11 = 0.f;
  for (int cb = s * 256; cb < s * 256 + 256; cb += 128) {
    __syncthreads();
#pragma unroll
    for (int q = 0; q < 4; ++q) {
      const float4 v = *(const float4*)(UM + (size_t)(i0 + r0) * N_DIM + cb + sg + q * 4);
      *(float4*)&Vs[r0 * 132 + sg + q * 4] = v;
    }
    __syncthreads();
#pragma unroll 8
    for (int c = 0; c < 128; c += 4) {
      const float4 va0 = *(const float4*)&Vs[a2 * 132 + c];
      const float4 va1 = *(const float4*)&Vs[(a2 + 1) * 132 + c];
      const float4 vb0 = *(const float4*)&Vs[b2 * 132 + c];
      const float4 vb1 = *(const float4*)&Vs[(b2 + 1) * 132 + c];
      s00 = fmaf(va0.x, vb0.x, s00); s00 = fmaf(va0.y, vb0.y, s00);
      s00 = fmaf(va0.z, vb0.z, s00); s00 = fmaf(va0.w, vb0.w, s00);
      s01 = fmaf(va0.x, vb1.x, s01); s01 = fmaf(va0.y, vb1.y, s01);
      s01 = fmaf(va0.z, vb1.z, s01); s01 = fmaf(va0.w, vb1.w, s01);
      s10 = fmaf(va1.x, vb0.x, s10); s10 = fmaf(va1.y, vb0.y, s10);
      s10 = fmaf(va1.z, vb0.z, s10); s10 = fmaf(va1.w, vb0.w, s10);
      s11 = fmaf(va1.x, vb1.x, s11); s11 = fmaf(va1.y, vb1.y, s11);
      s11 = fmaf(va1.z, vb1.z, s11); s11 = fmaf(va1.w, vb1.w, s11);
    }
  }
  dst[a2 * 32 + b2] = s00;
  dst[a2 * 32 + b2 + 1] = s01;
  dst[(a2 + 1) * 32 + b2] = s10;
  dst[(a2 + 1) * 32 + b2 + 1] = s11;
}

__global__ __launch_bounds__(256)
void t32_kernel(const float* __restrict__ Pg, float* __restrict__ Tg) {
  __shared__ float Sg[32 * 33];
  __shared__ float Ts[32 * 33];
  const int g = blockIdx.x;
  const int t = threadIdx.x;
#pragma unroll
  for (int q = 0; q < 4; ++q) {
    const int e = t * 4 + q;
    float ssum = 0.f;
    for (int s = 0; s < 8; ++s) ssum += Pg[(size_t)(g * 8 + s) * 1024 + e];
    Sg[(e >> 5) * 33 + (e & 31)] = ssum;
  }
  __syncthreads();
  for (int j = 0; j < 32; ++j) {
    if (t < 32) {
      const float sjj = Sg[j * 33 + j];
      const float bj = (sjj > 0.f) ? 2.0f / sjj : 0.f;
      float val;
      if (t == j) val = bj;
      else if (t > j) val = 0.f;
      else {
        float acc = 0.f;
        for (int ll = t; ll < j; ++ll)
          acc = fmaf(Ts[t * 33 + ll], Sg[ll * 33 + j], acc);
        val = -bj * acc;
      }
      Ts[t * 33 + j] = val;
    }
    __syncthreads();
  }
#pragma unroll
  for (int q = 0; q < 4; ++q) {
    const int e = t * 4 + q;
    Tg[(size_t)g * 1024 + e] = Ts[(e >> 5) * 33 + (e & 31)];
  }
}

__global__ __launch_bounds__(256)
void wt32_kernel(const float* __restrict__ UM, const float* __restrict__ Tg,
                 float* __restrict__ WT) {
  const int g = blockIdx.x >> 4;
  const int ctile = blockIdx.x & 15;
  const int i0 = g * 32;
  const int cb = ctile * 128;
  const int t = threadIdx.x;
  const int jh = t >> 6;
  const int cc = (t & 63) * 2;
  if (cb + 128 <= i0) {                      // zero region (poisoned ws!)
#pragma unroll
    for (int jj = 0; jj < 8; ++jj) {
      const int j = jh * 8 + jj;
      *(float2*)(WT + (size_t)(i0 + j) * N_DIM + cb + cc) = make_float2(0.f, 0.f);
    }
    return;
  }
  __shared__ float Vs[32 * 132];
  __shared__ float Ts[32 * 33];
#pragma unroll
  for (int q = 0; q < 4; ++q) {
    const int e = t * 4 + q;
    Ts[(e >> 5) * 33 + (e & 31)] = Tg[(size_t)g * 1024 + e];
  }
  const int r0 = t >> 3, sg = (t & 7) * 16;
#pragma unroll
  for (int q = 0; q < 4; ++q) {
    const float4 v = *(const float4*)(UM + (size_t)(i0 + r0) * N_DIM + cb + sg + q * 4);
    *(float4*)&Vs[r0 * 132 + sg + q * 4] = v;
  }
  __syncthreads();
#pragma unroll
  for (int jj = 0; jj < 8; ++jj) {
    const int j = jh * 8 + jj;
    float acc0 = 0.f, acc1 = 0.f;
    for (int ll = 0; ll <= j; ++ll) {
      const float tv = Ts[ll * 33 + j];
      acc0 = fmaf(tv, Vs[ll * 132 + cc], acc0);
      acc1 = fmaf(tv, Vs[ll * 132 + cc + 1], acc1);
    }
    *(float2*)(WT + (size_t)(i0 + j) * N_DIM + cb + cc) = make_float2(acc0, acc1);
  }
}

// =================== fp32 GEMM cores (small-k ladder, proven) ===================

__device__ __forceinline__
void nt_core(const float* __restrict__ A, int Ma,
             const float* __restrict__ B, int Nb,
             float* __restrict__ C, int ldc,
             int mb, int nb, int cbeg, int cend) {
  __shared__ float As[16][68];
  __shared__ float Bs[16][68];
  const int tid = threadIdx.x;
  const int tn = tid & 15, tm = tid >> 4;
  const int rowl = tid >> 2;
  const int kq = (tid & 3) << 2;
  float acc[4][4] = {};

  for (int c = cbeg; c < cend; c += 16) {
    {
      const int r = mb + rowl;
      float4 v = make_float4(0.f, 0.f, 0.f, 0.f);
      if (r < Ma) v = *(const float4*)(A + (size_t)r * N_DIM + c + kq);
      As[kq + 0][rowl] = v.x; As[kq + 1][rowl] = v.y;
      As[kq + 2][rowl] = v.z; As[kq + 3][rowl] = v.w;
      const int r2 = nb + rowl;
      float4 u = make_float4(0.f, 0.f, 0.f, 0.f);
      if (r2 < Nb) u = *(const float4*)(B + (size_t)r2 * N_DIM + c + kq);
      Bs[kq + 0][rowl] = u.x; Bs[kq + 1][rowl] = u.y;
      Bs[kq + 2][rowl] = u.z; Bs[kq + 3][rowl] = u.w;
    }
    __syncthreads();
#pragma unroll
    for (int kk = 0; kk < 16; ++kk) {
      const float4 a4 = *(const float4*)&As[kk][tm * 4];
      const float4 b4 = *(const float4*)&Bs[kk][tn * 4];
      acc[0][0] = fmaf(a4.x, b4.x, acc[0][0]);
      acc[0][1] = fmaf(a4.x, b4.y, acc[0][1]);
      acc[0][2] = fmaf(a4.x, b4.z, acc[0][2]);
      acc[0][3] = fmaf(a4.x, b4.w, acc[0][3]);
      acc[1][0] = fmaf(a4.y, b4.x, acc[1][0]);
      acc[1][1] = fmaf(a4.y, b4.y, acc[1][1]);
      acc[1][2] = fmaf(a4.y, b4.z, acc[1][2]);
      acc[1][3] = fmaf(a4.y, b4.w, acc[1][3]);
      acc[2][0] = fmaf(a4.z, b4.x, acc[2][0]);
      acc[2][1] = fmaf(a4.z, b4.y, acc[2][1]);
      acc[2][2] = fmaf(a4.z, b4.z, acc[2][2]);
      acc[2][3] = fmaf(a4.z, b4.w, acc[2][3]);
      acc[3][0] = fmaf(a4.w, b4.x, acc[3][0]);
      acc[3][1] = fmaf(a4.w, b4.y, acc[3][1]);
      acc[3][2] = fmaf(a4.w, b4.z, acc[3][2]);
      acc[3][3] = fmaf(a4.w, b4.w, acc[3][3]);
    }
    __syncthreads();
  }

#pragma unroll
  for (int i = 0; i < 4; ++i) {
    const int r = mb + tm * 4 + i;
    if (r < Ma) {
#pragma unroll
      for (int jj = 0; jj < 4; ++jj) {
        const int q = nb + tn * 4 + jj;
        if (q < Nb) C[(size_t)r * ldc + q] = acc[i][jj];
      }
    }
  }
}

__device__ __forceinline__
void nn_core(const float* __restrict__ A, int Ma, int Ka, int lda,
             const float* __restrict__ B,
             const float* __restrict__ C0, float* __restrict__ out,
             int rb, int cb) {
  __shared__ float As[16][68];
  __shared__ float Bs[16][64];
  const int tid = threadIdx.x;
  const int tn = tid & 15, tm = tid >> 4;
  const int rowl = tid >> 2;
  const int kq = (tid & 3) << 2;
  const int kkb = tid >> 4;
  const int cc4 = (tid & 15) << 2;
  float acc[4][4] = {};

  for (int J = 0; J < Ka; J += 16) {
    {
      const int r = rb + rowl;
#pragma unroll
      for (int t = 0; t < 4; ++t) {
        const int Jc = J + kq + t;
        As[kq + t][rowl] = (r < Ma && Jc < Ka) ? A[(size_t)r * lda + Jc] : 0.f;
      }
      const int Jr = J + kkb;
      float4 v = make_float4(0.f, 0.f, 0.f, 0.f);
      if (Jr < Ka) v = *(const float4*)(B + (size_t)Jr * N_DIM + cb + cc4);
      *(float4*)&Bs[kkb][cc4] = v;
    }
    __syncthreads();
#pragma unroll
    for (int kk = 0; kk < 16; ++kk) {
      const float4 a4 = *(const float4*)&As[kk][tm * 4];
      const float4 b4 = *(const float4*)&Bs[kk][tn * 4];
      acc[0][0] = fmaf(a4.x, b4.x, acc[0][0]);
      acc[0][1] = fmaf(a4.x, b4.y, acc[0][1]);
      acc[0][2] = fmaf(a4.x, b4.z, acc[0][2]);
      acc[0][3] = fmaf(a4.x, b4.w, acc[0][3]);
      acc[1][0] = fmaf(a4.y, b4.x, acc[1][0]);
      acc[1][1] = fmaf(a4.y, b4.y, acc[1][1]);
      acc[1][2] = fmaf(a4.y, b4.z, acc[1][2]);
      acc[1][3] = fmaf(a4.y, b4.w, acc[1][3]);
      acc[2][0] = fmaf(a4.z, b4.x, acc[2][0]);
      acc[2][1] = fmaf(a4.z, b4.y, acc[2][1]);
      acc[2][2] = fmaf(a4.z, b4.z, acc[2][2]);
      acc[2][3] = fmaf(a4.z, b4.w, acc[2][3]);
      acc[3][0] = fmaf(a4.w, b4.x, acc[3][0]);
      acc[3][1] = fmaf(a4.w, b4.y, acc[3][1]);
      acc[3][2] = fmaf(a4.w, b4.z, acc[3][2]);
      acc[3][3] = fmaf(a4.w, b4.w, acc[3][3]);
    }
    __syncthreads();
  }

#pragma unroll
  for (int i = 0; i < 4; ++i) {
    const int r = rb + tm * 4 + i;
    if (r < Ma) {
#pragma unroll
      for (int jj = 0; jj < 4; ++jj) {
        const int c = cb + tn * 4 + jj;
        out[(size_t)r * N_DIM + c] = C0[(size_t)r * N_DIM + c] - acc[i][jj];
      }
    }
  }
}

// =================== fp32 merge wrappers (k = 32, 64) ===================

__global__ __launch_bounds__(256)
void merge_ct_splitk(const float* __restrict__ WT, const float* __restrict__ UM,
                     float* __restrict__ Pt, int k, int SK) {
  const int tpm = (k + 63) >> 6;
  const int tiles = tpm * tpm;
  const int per_pair = tiles * SK;
  const int m = blockIdx.x / per_pair;
  const int rest = blockIdx.x % per_pair;
  const int sk = rest / tiles;
  const int t2 = rest % tiles;
  const int mb = (t2 / tpm) * 64;
  const int nb = (t2 % tpm) * 64;
  const int a0 = 2 * k * m, b0 = a0 + k;
  const int c0 = b0 & ~15;
  const int len = N_DIM - c0;
  const int step = ((len + SK - 1) / SK + 15) & ~15;
  int cbeg = c0 + sk * step;
  int cend = cbeg + step;
  if (cbeg > N_DIM) cbeg = N_DIM;
  if (cend > N_DIM) cend = N_DIM;
  const int mm = N_DIM / (2 * k);
  float* dst = Pt + (size_t)sk * mm * k * k + (size_t)m * k * k;
  nt_core(WT + (size_t)b0 * N_DIM, k, UM + (size_t)a0 * N_DIM, k,
          dst, k, mb, nb, cbeg, cend);
}

__global__ __launch_bounds__(256)
void ct_reduce(const float* __restrict__ Pt, float* __restrict__ Ct,
               int n, int SK) {
  const int i4 = (blockIdx.x * 256 + threadIdx.x) * 4;
  if (i4 >= n) return;
  float4 s = *(const float4*)(Pt + i4);
  for (int sk = 1; sk < SK; ++sk) {
    const float4 v = *(const float4*)(Pt + (size_t)sk * n + i4);
    s.x += v.x; s.y += v.y; s.z += v.z; s.w += v.w;
  }
  *(float4*)(Ct + i4) = s;
}

__global__ __launch_bounds__(256)
void merge_update_kernel(float* __restrict__ WT, const float* __restrict__ Ct,
                         int k) {
  const int tpr = (k + 63) >> 6;
  const int tiles = tpr * NT64;
  const int m = blockIdx.x / tiles;
  const int t = blockIdx.x % tiles;
  const int rb = (t / NT64) * 64;
  const int cb = (t % NT64) * 64;
  const int a0 = 2 * k * m, b0 = a0 + k;
  if (cb + 64 <= a0) return;
  nn_core(Ct + (size_t)m * k * k, k, k, k,
          WT + (size_t)a0 * N_DIM,
          WT + (size_t)b0 * N_DIM, WT + (size_t)b0 * N_DIM, rb, cb);
}

// =================== MFMA staging helpers (BK=32, stride 40) ===================

__device__ __forceinline__ void stage_f32ld(const float* __restrict__ src,
                                            int rb, int kb, int t, int ld,
                                            ushort_t* __restrict__ Hd,
                                            ushort_t* __restrict__ Ld) {
  const int r0 = t >> 3;
  const int seg = (t & 7) * 4;
#pragma unroll
  for (int p = 0; p < 4; ++p) {
    const int row = r0 + p * 32;
    const float4 v = *(const float4*)(src + (size_t)(rb + row) * ld + kb + seg);
    const float f[4] = {v.x, v.y, v.z, v.w};
    ushort_t h[4], l[4];
#pragma unroll
    for (int q = 0; q < 4; ++q) {
      h[q] = f2bf_rtne(f[q]);
      l[q] = f2bf_rtne(f[q] - bf2f(h[q]));
    }
    const int o = row * 40 + seg;
    *(uint2*)(Hd + o) = make_uint2((unsigned)h[0] | ((unsigned)h[1] << 16),
                                   (unsigned)h[2] | ((unsigned)h[3] << 16));
    *(uint2*)(Ld + o) = make_uint2((unsigned)l[0] | ((unsigned)l[1] << 16),
                                   (unsigned)l[2] | ((unsigned)l[3] << 16));
  }
}

// A-staging for update: sum SK split-K partial slices while staging.
__device__ __forceinline__ void stage_a_sum(const float* __restrict__ Pt,
                                            size_t pairoff, size_t slice, int SK,
                                            int rb, int J, int t, int ld,
                                            ushort_t* __restrict__ Hd,
                                            ushort_t* __restrict__ Ld) {
  const int r0 = t >> 3;
  const int seg = (t & 7) * 4;
#pragma unroll
  for (int p = 0; p < 4; ++p) {
    const int row = r0 + p * 32;
    const float* src = Pt + pairoff + (size_t)(rb + row) * ld + J + seg;
    float f[4] = {0.f, 0.f, 0.f, 0.f};
    for (int s = 0; s < SK; ++s) {
      const float4 v = *(const float4*)(src + slice * s);
      f[0] += v.x; f[1] += v.y; f[2] += v.z; f[3] += v.w;
    }
    ushort_t h[4], l[4];
#pragma unroll
    for (int q = 0; q < 4; ++q) {
      h[q] = f2bf_rtne(f[q]);
      l[q] = f2bf_rtne(f[q] - bf2f(h[q]));
    }
    const int o = row * 40 + seg;
    *(uint2*)(Hd + o) = make_uint2((unsigned)h[0] | ((unsigned)h[1] << 16),
                                   (unsigned)h[2] | ((unsigned)h[3] << 16));
    *(uint2*)(Ld + o) = make_uint2((unsigned)l[0] | ((unsigned)l[1] << 16),
                                   (unsigned)l[2] | ((unsigned)l[3] << 16));
  }
}

// B[J+kk][cb+n] (row-major ld N_DIM) -> Bs[n][kk] (transposed, stride 40)
__device__ __forceinline__ void stage_b_trans(const float* __restrict__ B,
                                              int J, int cb, int t,
                                              ushort_t* __restrict__ Hd,
                                              ushort_t* __restrict__ Ld) {
  const int kk8 = t >> 5;
  const int nq = (t & 31) * 4;
#pragma unroll
  for (int p = 0; p < 4; ++p) {
    const int kk = kk8 * 4 + p;
    const float4 v = *(const float4*)(B + (size_t)(J + kk) * N_DIM + cb + nq);
    const float f[4] = {v.x, v.y, v.z, v.w};
#pragma unroll
    for (int e = 0; e < 4; ++e) {
      const ushort_t h = f2bf_rtne(f[e]);
      Hd[(nq + e) * 40 + kk] = h;
      Ld[(nq + e) * 40 + kk] = f2bf_rtne(f[e] - bf2f(h));
    }
  }
}

__device__ __forceinline__ void stage_pre(const ushort_t* __restrict__ H,
                                          const ushort_t* __restrict__ L,
                                          int rb, int kb, int t,
                                          ushort_t* __restrict__ Hd,
                                          ushort_t* __restrict__ Ld) {
  const int r0 = t >> 1;
  const int seg = (t & 1) << 4;
  const size_t g = (size_t)(rb + r0) * N_DIM + kb + seg;
  const int o = r0 * 40 + seg;
  *(bf16x8*)(Hd + o) = *(const bf16x8*)(H + g);
  *(bf16x8*)(Hd + o + 8) = *(const bf16x8*)(H + g + 8);
  *(bf16x8*)(Ld + o) = *(const bf16x8*)(L + g);
  *(bf16x8*)(Ld + o + 8) = *(const bf16x8*)(L + g + 8);
}

// =================== MFMA merge kernels (k >= 128) ===================

// Pt slice: Ct[q][p] = sum_{c in sk-range} WT[b0+q][c] * UM[a0+p][c]
__global__ __launch_bounds__(256)
void mct_mfma(const float* __restrict__ WT,
              const ushort_t* __restrict__ UMh, const ushort_t* __restrict__ UMl,
              float* __restrict__ Pt, int k, int SK) {
  const int tpk = k >> 7;
  const int tiles = tpk * tpk;
  const int per_pair = tiles * SK;
  const int m = blockIdx.x / per_pair;
  const int rest = blockIdx.x % per_pair;
  const int sk = rest / tiles;
  const int t2 = rest % tiles;
  const int mb = (t2 / tpk) * 128;
  const int nb = (t2 % tpk) * 128;
  const int a0 = 2 * k * m, b0 = a0 + k;
  const int mm = N_DIM / (2 * k);
  const int len = N_DIM - b0;
  const int step = ((len + SK - 1) / SK + 31) & ~31;
  int cbeg = b0 + sk * step;
  int cend = cbeg + step;
  if (cbeg > N_DIM) cbeg = N_DIM;
  if (cend > N_DIM) cend = N_DIM;
  float* outp = Pt + (size_t)sk * mm * k * k + (size_t)m * k * k;

  __shared__ ushort_t Ahs[128 * 40], Als[128 * 40], Bhs[128 * 40], Bls[128 * 40];
  const int t = threadIdx.x;
  const int l = t & 63, w = t >> 6;
  const int wm = w >> 1, wn = w & 1;
  const int lrow = l & 15, lk = l >> 4;

  f32x4 acc[4][4];
#pragma unroll
  for (int i = 0; i < 4; ++i)
#pragma unroll
    for (int j = 0; j < 4; ++j) {
      acc[i][j][0] = 0.f; acc[i][j][1] = 0.f;
      acc[i][j][2] = 0.f; acc[i][j][3] = 0.f;
    }

  for (int kb = cbeg; kb < cend; kb += 32) {
    __syncthreads();
    stage_f32ld(WT + (size_t)b0 * N_DIM, mb, kb, t, N_DIM, Ahs, Als);
    stage_pre(UMh + (size_t)a0 * N_DIM, UMl + (size_t)a0 * N_DIM, nb, kb, t, Bhs, Bls);
    __syncthreads();

    bf16x8 ah[4], al[4], bh[4], bl[4];
#pragma unroll
    for (int fm = 0; fm < 4; ++fm) {
      const int o = (wm * 64 + fm * 16 + lrow) * 40 + lk * 8;
      ah[fm] = *(const bf16x8*)(Ahs + o);
      al[fm] = *(const bf16x8*)(Als + o);
    }
#pragma unroll
    for (int fn = 0; fn < 4; ++fn) {
      const int o = (wn * 64 + fn * 16 + lrow) * 40 + lk * 8;
      bh[fn] = *(const bf16x8*)(Bhs + o);
      bl[fn] = *(const bf16x8*)(Bls + o);
    }
#pragma unroll
    for (int fm = 0; fm < 4; ++fm)
#pragma unroll
      for (int fn = 0; fn < 4; ++fn) {
        acc[fm][fn] = __builtin_amdgcn_mfma_f32_16x16x32_bf16(ah[fm], bh[fn], acc[fm][fn], 0, 0, 0);
        acc[fm][fn] = __builtin_amdgcn_mfma_f32_16x16x32_bf16(ah[fm], bl[fn], acc[fm][fn], 0, 0, 0);
        acc[fm][fn] = __builtin_amdgcn_mfma_f32_16x16x32_bf16(al[fm], bh[fn], acc[fm][fn], 0, 0, 0);
      }
  }

#pragma unroll
  for (int fm = 0; fm < 4; ++fm) {
    const int m0 = mb + wm * 64 + fm * 16 + lk * 4;
#pragma unroll
    for (int fn = 0; fn < 4; ++fn) {
      const int n = nb + wn * 64 + fn * 16 + lrow;
#pragma unroll
      for (int r = 0; r < 4; ++r)
        outp[(size_t)(m0 + r) * k + n] = acc[fm][fn][r];
    }
  }
}

// WT_b[q][c] -= sum_p Ct[q][p] * WT_a[p][c]; A = sum of SK Pt slices.
__global__ __launch_bounds__(256)
void mupd_mfma(float* __restrict__ WT, const float* __restrict__ Pt,
               int k, int SK) {
  const int tpk = k >> 7;
  const int tiles = tpk * NT128;
  const int m = blockIdx.x / tiles;
  const int rest = blockIdx.x % tiles;
  const int rb = (rest / NT128) * 128;
  const int cb = (rest % NT128) * 128;
  const int a0 = 2 * k * m, b0 = a0 + k;
  if (cb + 128 <= a0) return;
  const int mm = N_DIM / (2 * k);
  const size_t pairoff = (size_t)m * k * k;
  const size_t slice = (size_t)mm * k * k;
  const float* Bw = WT + (size_t)a0 * N_DIM;
  float* C = WT + (size_t)b0 * N_DIM;

  __shared__ ushort_t Ahs[128 * 40], Als[128 * 40], Bhs[128 * 40], Bls[128 * 40];
  const int t = threadIdx.x;
  const int l = t & 63, w = t >> 6;
  const int wm = w >> 1, wn = w & 1;
  const int lrow = l & 15, lk = l >> 4;

  f32x4 acc[4][4];
#pragma unroll
  for (int i = 0; i < 4; ++i)
#pragma unroll
    for (int j = 0; j < 4; ++j) {
      acc[i][j][0] = 0.f; acc[i][j][1] = 0.f;
      acc[i][j][2] = 0.f; acc[i][j][3] = 0.f;
    }

  for (int J = 0; J < k; J += 32) {
    __syncthreads();
    stage_a_sum(Pt, pairoff, slice, SK, rb, J, t, k, Ahs, Als);
    stage_b_trans(Bw, J, cb, t, Bhs, Bls);
    __syncthreads();

    bf16x8 ah[4], al[4], bh[4], bl[4];
#pragma unroll
    for (int fm = 0; fm < 4; ++fm) {
      const int o = (wm * 64 + fm * 16 + lrow) * 40 + lk * 8;
      ah[fm] = *(const bf16x8*)(Ahs + o);
      al[fm] = *(const bf16x8*)(Als + o);
    }
#pragma unroll
    for (int fn = 0; fn < 4; ++fn) {
      const int o = (wn * 64 + fn * 16 + lrow) * 40 + lk * 8;
      bh[fn] = *(const bf16x8*)(Bhs + o);
      bl[fn] = *(const bf16x8*)(Bls + o);
    }
#pragma unroll
    for (int fm = 0; fm < 4; ++fm)
#pragma unroll
      for (int fn = 0; fn < 4; ++fn) {
        acc[fm][fn] = __builtin_amdgcn_mfma_f32_16x16x32_bf16(ah[fm], bh[fn], acc[fm][fn], 0, 0, 0);
        acc[fm][fn] = __builtin_amdgcn_mfma_f32_16x16x32_bf16(ah[fm], bl[fn], acc[fm][fn], 0, 0, 0);
        acc[fm][fn] = __builtin_amdgcn_mfma_f32_16x16x32_bf16(al[fm], bh[fn], acc[fm][fn], 0, 0, 0);
      }
  }

#pragma unroll
  for (int fm = 0; fm < 4; ++fm) {
    const int m0 = rb + wm * 64 + fm * 16 + lk * 4;
#pragma unroll
    for (int fn = 0; fn < 4; ++fn) {
      const int n = cb + wn * 64 + fn * 16 + lrow;
#pragma unroll
      for (int r = 0; r < 4; ++r) {
        const size_t idx = (size_t)(m0 + r) * N_DIM + n;
        C[idx] = C[idx] - acc[fm][fn][r];
      }
    }
  }
}

// =================== trans_conv ===================

__global__ __launch_bounds__(256)
void trans_conv_kernel(const float* __restrict__ WT,
                       ushort_t* __restrict__ WTTh, ushort_t* __restrict__ WTTl) {
  __shared__ float Tt[64 * 65];
  const int t = threadIdx.x;
  const int bk = (blockIdx.x & 31) * 64;
  const int bn = (blockIdx.x >> 5) * 64;
  const int r = t >> 2;
  const int s = (t & 3) * 16;
#pragma unroll
  for (int q = 0; q < 4; ++q) {
    const float4 v = *(const float4*)(WT + (size_t)(bk + r) * N_DIM + bn + s + q * 4);
    Tt[r * 65 + s + q * 4 + 0] = v.x;
    Tt[r * 65 + s + q * 4 + 1] = v.y;
    Tt[r * 65 + s + q * 4 + 2] = v.z;
    Tt[r * 65 + s + q * 4 + 3] = v.w;
  }
  __syncthreads();
#pragma unroll
  for (int q = 0; q < 4; ++q) {
    float f[4];
    f[0] = Tt[(s + q * 4 + 0) * 65 + r];
    f[1] = Tt[(s + q * 4 + 1) * 65 + r];
    f[2] = Tt[(s + q * 4 + 2) * 65 + r];
    f[3] = Tt[(s + q * 4 + 3) * 65 + r];
    ushort_t h[4], l[4];
#pragma unroll
    for (int e = 0; e < 4; ++e) {
      h[e] = f2bf_rtne(f[e]);
      l[e] = f2bf_rtne(f[e] - bf2f(h[e]));
    }
    const size_t o = (size_t)(bn + r) * N_DIM + bk + s + q * 4;
    *(uint2*)(WTTh + o) = make_uint2((unsigned)h[0] | ((unsigned)h[1] << 16),
                                     (unsigned)h[2] | ((unsigned)h[3] << 16));
    *(uint2*)(WTTl + o) = make_uint2((unsigned)l[0] | ((unsigned)l[1] << 16),
                                     (unsigned)l[2] | ((unsigned)l[3] << 16));
  }
}

// =================== MFMA application GEMMs (BK = 64) ===================

__device__ __forceinline__ void stage_f32_64(const float* __restrict__ src,
                                             int rb, int kb, int t, int ld,
                                             ushort_t* __restrict__ Hd,
                                             ushort_t* __restrict__ Ld) {
  const int r0 = t >> 3;
  const int seg = (t & 7) * 8;
#pragma unroll
  for (int p = 0; p < 4; ++p) {
    const int row = r0 + p * 32;
#pragma unroll
    for (int q2 = 0; q2 < 8; q2 += 4) {
      const float4 v = *(const float4*)(src + (size_t)(rb + row) * ld + kb + seg + q2);
      const float f[4] = {v.x, v.y, v.z, v.w};
      ushort_t h[4], l[4];
#pragma unroll
      for (int q = 0; q < 4; ++q) {
        h[q] = f2bf_rtne(f[q]);
        l[q] = f2bf_rtne(f[q] - bf2f(h[q]));
      }
      const int o = row * 72 + seg + q2;
      *(uint2*)(Hd + o) = make_uint2((unsigned)h[0] | ((unsigned)h[1] << 16),
                                     (unsigned)h[2] | ((unsigned)h[3] << 16));
      *(uint2*)(Ld + o) = make_uint2((unsigned)l[0] | ((unsigned)l[1] << 16),
                                     (unsigned)l[2] | ((unsigned)l[3] << 16));
    }
  }
}

__device__ __forceinline__ void stage_pre_64(const ushort_t* __restrict__ H,
                                             const ushort_t* __restrict__ L,
                                             int rb, int kb, int t,
                                             ushort_t* __restrict__ Hd,
                                             ushort_t* __restrict__ Ld) {
  const int r0 = t >> 1;
  const int seg = (t & 1) << 5;        // 0 or 32 shorts
  const size_t g = (size_t)(rb + r0) * N_DIM + kb + seg;
  const int o = r0 * 72 + seg;
#pragma unroll
  for (int q = 0; q < 32; q += 8) {
    *(bf16x8*)(Hd + o + q) = *(const bf16x8*)(H + g + q);
    *(bf16x8*)(Ld + o + q) = *(const bf16x8*)(L + g + q);
  }
}

// ASRC: 1 = A fp32 (convert on fly), 0 = A pre-split bf16 pair.
// EP:   1 = Cf = X - acc ;  2 = write Ch/Cl = bf16split(acc).
template <int ASRC, int EP>
__global__ __launch_bounds__(256)
void gemm_bf_kernel(const float* __restrict__ Af,
                    const ushort_t* __restrict__ Ahg, const ushort_t* __restrict__ Alg,
                    const ushort_t* __restrict__ Bhg, const ushort_t* __restrict__ Blg,
                    const float* __restrict__ X, float* __restrict__ Cf,
                    ushort_t* __restrict__ Ch, ushort_t* __restrict__ Cl,
                    int tri) {
  __shared__ ushort_t Ahs[128 * 72], Als[128 * 72], Bhs[128 * 72], Bls[128 * 72];
  const int t = threadIdx.x;
  const int l = t & 63, w = t >> 6;
  const int wm = w >> 1, wn = w & 1;
  const int lrow = l & 15, lk = l >> 4;

  int bid = blockIdx.x;
  const int nwg = gridDim.x;
  if ((nwg & 7) == 0) {
    const int q = nwg >> 3;
    bid = (bid & 7) * q + (bid >> 3);
  }
  const int mb = (bid / NT128) * 128;
  const int nb = (bid % NT128) * 128;
  const int k0 = tri ? nb : 0;

  f32x4 acc[4][4];
#pragma unroll
  for (int i = 0; i < 4; ++i)
#pragma unroll
    for (int j = 0; j < 4; ++j) {
      acc[i][j][0] = 0.f; acc[i][j][1] = 0.f;
      acc[i][j][2] = 0.f; acc[i][j][3] = 0.f;
    }

  for (int kb = k0; kb < N_DIM; kb += 64) {
    __syncthreads();
    if (ASRC) stage_f32_64(Af, mb, kb, t, N_DIM, Ahs, Als);
    else      stage_pre_64(Ahg, Alg, mb, kb, t, Ahs, Als);
    stage_pre_64(Bhg, Blg, nb, kb, t, Bhs, Bls);
    __syncthreads();

#pragma unroll
    for (int half = 0; half < 2; ++half) {
      bf16x8 ah[4], al[4], bh[4], bl[4];
#pragma unroll
      for (int fm = 0; fm < 4; ++fm) {
        const int o = (wm * 64 + fm * 16 + lrow) * 72 + half * 32 + lk * 8;
        ah[fm] = *(const bf16x8*)(Ahs + o);
        al[fm] = *(const bf16x8*)(Als + o);
      }
#pragma unroll
      for (int fn = 0; fn < 4; ++fn) {
        const int o = (wn * 64 + fn * 16 + lrow) * 72 + half * 32 + lk * 8;
        bh[fn] = *(const bf16x8*)(Bhs + o);
        bl[fn] = *(const bf16x8*)(Bls + o);
      }
#pragma unroll
      for (int fm = 0; fm < 4; ++fm)
#pragma unroll
        for (int fn = 0; fn < 4; ++fn) {
          acc[fm][fn] = __builtin_amdgcn_mfma_f32_16x16x32_bf16(ah[fm], bh[fn], acc[fm][fn], 0, 0, 0);
          acc[fm][fn] = __builtin_amdgcn_mfma_f32_16x16x32_bf16(ah[fm], bl[fn], acc[fm][fn], 0, 0, 0);
          acc[fm][fn] = __builtin_amdgcn_mfma_f32_16x16x32_bf16(al[fm], bh[fn], acc[fm][fn], 0, 0, 0);
        }
    }
  }

#pragma unroll
  for (int fm = 0; fm < 4; ++fm) {
    const int m0 = mb + wm * 64 + fm * 16 + lk * 4;
#pragma unroll
    for (int fn = 0; fn < 4; ++fn) {
      const int n = nb + wn * 64 + fn * 16 + lrow;
#pragma unroll
      for (int r = 0; r < 4; ++r) {
        const size_t idx = (size_t)(m0 + r) * N_DIM + n;
        const float f = acc[fm][fn][r];
        if (EP == 1) {
          Cf[idx] = X[idx] - f;
        } else {
          const ushort_t h = f2bf_rtne(f);
          Ch[idx] = h;
          Cl[idx] = f2bf_rtne(f - bf2f(h));
        }
      }
    }
  }
}

// =================== fallback sweep (round-2, proven) ===================

#define NRF 32
#define VCF 2
#define KGF 8
#define WPBF 4
#define NGRAMF ((KGF * (KGF + 1)) / 2)
#define NREDF (NGRAMF + KGF * VCF)

__device__ __forceinline__ void accum_group_f(const float (&u)[KGF],
                                              const float (&hr)[VCF],
                                              float (&red)[NREDF]) {
#pragma unroll
  for (int j = 0; j < KGF; ++j) {
#pragma unroll
    for (int l = 0; l <= j; ++l)
      red[(j * (j + 1)) / 2 + l] = fmaf(u[j], u[l], red[(j * (j + 1)) / 2 + l]);
#pragma unroll
    for (int c = 0; c < VCF; ++c)
      red[NGRAMF + j * VCF + c] = fmaf(u[j], hr[c], red[NGRAMF + j * VCF + c]);
  }
}

__global__ __launch_bounds__(256, 2)
void fallback_sweep_kernel(const float* __restrict__ x,
                           const float* __restrict__ w,
                           float* __restrict__ out) {
  const int lane = threadIdx.x & 63;
  const int wave = threadIdx.x >> 6;
  const int gw = blockIdx.x * WPBF + wave;
  const int col0 = gw * VCF;
  float h[NRF][VCF];
#pragma unroll
  for (int k = 0; k < NRF; ++k) {
    const int r = lane + 64 * k;
#pragma unroll
    for (int c = 0; c < VCF; ++c) h[k][c] = x[(size_t)(col0 + c) * N_DIM + r];
  }
  for (int i0 = N_DIM - KGF; i0 >= 0; i0 -= KGF) {
    const int ks = i0 >> 6;
    const float* wb = w + (size_t)i0 * N_DIM;
    float red[NREDF];
#pragma unroll
    for (int t = 0; t < NREDF; ++t) red[t] = 0.f;
#pragma unroll
    for (int k = 0; k < NRF; ++k) {
      const int r = lane + 64 * k;
      if (k > ks) {
        float u[KGF];
#pragma unroll
        for (int j = 0; j < KGF; ++j) u[j] = wb[(size_t)j * N_DIM + r];
        accum_group_f(u, h[k], red);
      } else if (k == ks) {
        float u[KGF];
#pragma unroll
        for (int j = 0; j < KGF; ++j) {
          float tt = wb[(size_t)j * N_DIM + r];
          u[j] = (r >= i0 + j) ? tt : 0.f;
        }
        if (i0 == N_DIM - KGF && r == N_DIM - 1) u[KGF - 1] = 1.0f;
        accum_group_f(u, h[k], red);
      }
    }
#pragma unroll
    for (int m = 1; m < 64; m <<= 1)
#pragma unroll
      for (int t = 0; t < NREDF; ++t) red[t] += __shfl_xor(red[t], m, 64);
    float beta[KGF];
#pragma unroll
    for (int j = 0; j < KGF; ++j) {
      const float n2 = red[(j * (j + 1)) / 2 + j];
      beta[j] = (n2 > 0.f) ? 2.0f / n2 : 0.f;
    }
    float T[KGF][KGF];
#pragma unroll
    for (int j = 0; j < KGF; ++j) {
      T[j][j] = beta[j];
#pragma unroll
      for (int r0 = 0; r0 < j; ++r0) {
        float acc = 0.f;
#pragma unroll
        for (int l = r0; l < j; ++l)
          acc = fmaf(T[r0][l], red[(j * (j + 1)) / 2 + l], acc);
        T[r0][j] = -beta[j] * acc;
      }
    }
    float z[KGF][VCF];
#pragma unroll
    for (int j = 0; j < KGF; ++j)
#pragma unroll
      for (int c = 0; c < VCF; ++c) {
        float acc = 0.f;
#pragma unroll
        for (int l = j; l < KGF; ++l)
          acc = fmaf(T[j][l], red[NGRAMF + l * VCF + c], acc);
        z[j][c] = acc;
      }
#pragma unroll
    for (int k = 0; k < NRF; ++k) {
      const int r = lane + 64 * k;
      if (k >= ks) {
        float u[KGF];
#pragma unroll
        for (int j = 0; j < KGF; ++j) {
          float tt = wb[(size_t)j * N_DIM + r];
          u[j] = (k > ks || r >= i0 + j) ? tt : 0.f;
        }
        if (i0 == N_DIM - KGF && r == N_DIM - 1) u[KGF - 1] = 1.0f;
#pragma unroll
        for (int c = 0; c < VCF; ++c) {
          float acc = h[k][c];
#pragma unroll
          for (int j = 0; j < KGF; ++j) acc = fmaf(-u[j], z[j][c], acc);
          h[k][c] = acc;
        }
      }
    }
  }
#pragma unroll
  for (int k = 0; k < NRF; ++k) {
    const int r = lane + 64 * k;
#pragma unroll
    for (int c = 0; c < VCF; ++c)
      out[(size_t)(col0 + c) * N_DIM + r] = h[k][c];
  }
}

// =================== launch ===================

extern "C" void kernel_launch(void* const* d_in, const int* in_sizes, int n_in,
                              void* d_out, int out_size, void* d_ws, size_t ws_size,
                              hipStream_t stream) {
  const float* x = (const float*)d_in[0];
  const float* w = (const float*)d_in[1];
  float* out = (float*)d_out;
  const int Bsz = in_sizes[0] / N_DIM;      // 4096

  const size_t NW = (size_t)N_DIM * N_DIM;  // 4M floats
  float* ws = (float*)d_ws;

  float* WT = ws;                                   // [0, 4M)
  float* UM = ws + NW;                              // [4M, 8M), dead after k=64
  float* Ct = ws + 2 * NW;                          // [8M, 9M)  (ladder only)
  float* Pt = ws + 2 * NW + NW / 4;                 // [9M, 11M) (ladder only)
  float* Pg = Ct;                                   // base: 512K floats
  float* Tg = Ct + 512 * 1024;                      // base: 64K floats
  ushort_t* WTTh = (ushort_t*)(ws + 2 * NW);        // [8M,10M) after trans_conv
  ushort_t* WTTl = WTTh + NW;                       // [10M,12M)
  ushort_t* UMh = (ushort_t*)(ws + 3 * NW);         // [12M,14M) from prep_split
  ushort_t* UMl = UMh + NW;                         // [14M,16M)
  ushort_t* A1h = (ushort_t*)ws;                    // [0,4M)  after trans_conv
  ushort_t* A1l = (ushort_t*)(ws + NW);             // [4M,8M)

  const size_t need = 4 * NW * sizeof(float);       // 64 MB

  if (ws_size < need || (Bsz % 128) != 0) {
    fallback_sweep_kernel<<<Bsz / (VCF * WPBF), 256, 0, stream>>>(x, w, out);
    return;
  }

  prep_split_kernel<<<(int)(NW / 1024), 256, 0, stream>>>(w, UM, UMh, UMl);

  // base-32 WY build (parallel)
  gram32_partial<<<64 * 8, 256, 0, stream>>>(UM, Pg);
  t32_kernel<<<64, 256, 0, stream>>>(Pg, Tg);
  wt32_kernel<<<64 * 16, 256, 0, stream>>>(UM, Tg, WT);

  // merge ladder
  for (int k = 32; k <= N_DIM / 2; k <<= 1) {
    const int mm = N_DIM / (2 * k);
    if (k < 128) {
      const int tpm = (k + 63) >> 6;
      const int tiles = tpm * tpm;
      int SK = 256 / (mm * tiles);
      if (SK < 1) SK = 1;
      if (SK > 16) SK = 16;
      float* dst = (SK == 1) ? Ct : Pt;
      merge_ct_splitk<<<mm * tiles * SK, 256, 0, stream>>>(WT, UM, dst, k, SK);
      if (SK > 1) {
        const int n = mm * k * k;
        ct_reduce<<<(n + 1023) / 1024, 256, 0, stream>>>(Pt, Ct, n, SK);
      }
      merge_update_kernel<<<mm * tpm * NT64, 256, 0, stream>>>(WT, Ct, k);
    } else {
      const int tpk = k >> 7;
      const int tiles = tpk * tpk;
      const int SK = (k == 128) ? 16 : (k == 256) ? 8 : (k == 512) ? 4 : 2;
      mct_mfma<<<mm * tiles * SK, 256, 0, stream>>>(WT, UMh, UMl, Pt, k, SK);
      mupd_mfma<<<mm * tpk * NT128, 256, 0, stream>>>(WT, Pt, k, SK);
    }
  }

  trans_conv_kernel<<<1024, 256, 0, stream>>>(WT, WTTh, WTTl);

  const int grid = (Bsz / 128) * NT128;     // 512
  gemm_bf_kernel<1, 2><<<grid, 256, 0, stream>>>(
      x, nullptr, nullptr, UMh, UMl, nullptr, nullptr, A1h, A1l, 1);
  gemm_bf_kernel<0, 1><<<grid, 256, 0, stream>>>(
      nullptr, A1h, A1l, WTTh, WTTl, x, out, nullptr, nullptr, 0);
}

// Round 8
// 751.354 us; speedup vs baseline: 1.1431x; 1.1431x over previous
//
#include <hip/hip_runtime.h>

// OrthogonalTransform via gram + T-matrix (compact WY) + MFMA application.
//
// out = X Q^T, Q = H_0...H_{n-1}, U = triu(weight), U[-1,-1] = 1.
// Q = I - V T V^T (forward larft T). Identity: T^-1 + T^-T = S = V V^T.
// Merge: T_{a∪b} = [[Ta, -Ta S_ab Tc],[0, Tc]]  (S_ab = gram block).
// W = V T  ->  out = X - (X V) W^T.
//
// Pipeline (15 launches):
//   prep_split : UMh/UMl = bf16 hi/lo of masked triu rows
//   gram       : S upper tiles = UM UM^T (MFMA split-3, one launch)
//   memset     : T, Tt = 0
//   tbase64    : 32 groups, 64-step larft recurrence -> T/Tt diag blocks
//   merges     : k=64..1024: step1 P = Tt_c S_ab^T ; step2 Tt_ab = -P Ta^T
//                (fp32 64^2 core k<=256, MFMA 128^2 fp32-on-fly k>=512)
//   wbuild     : W[c][j] = sum_l UM[l][c] T[l][j]  (MFMA, A=UM^T staged)
//   gemm1      : A1h/l = bf16split(X UM^T)  (r6-proven, tri-skip)
//   gemm2      : out = X - A1 W^T           (r6-proven)
//
// ws (floats, 16M = 64 MB):
//   [0,4M)   S  (upper tiles; lower-left quadrant = P scratch) -> Wh/Wl after
//   [4,8M)   T   -> A1h after wbuild
//   [8,12M)  Tt  -> A1l after wbuild
//   [12,16M) UMh + UMl

#define NT 2048
#define NT128 16

typedef __attribute__((ext_vector_type(8))) short bf16x8;
typedef __attribute__((ext_vector_type(4))) float f32x4;
typedef unsigned short ushort_t;

__device__ __forceinline__ ushort_t f2bf_rtne(float f) {
  unsigned u = __builtin_bit_cast(unsigned, f);
  u += 0x7FFFu + ((u >> 16) & 1u);
  return (ushort_t)(u >> 16);
}
__device__ __forceinline__ float bf2f(ushort_t h) {
  return __builtin_bit_cast(float, (unsigned)h << 16);
}

// =================== prep: masked triu -> bf16 hi/lo ===================

__global__ __launch_bounds__(256)
void prep_split_kernel(const float* __restrict__ w,
                       ushort_t* __restrict__ UMh, ushort_t* __restrict__ UMl) {
  const size_t i4 = ((size_t)blockIdx.x * 256 + threadIdx.x) * 4;
  const int j = (int)(i4 >> 11);
  const int c = (int)(i4 & (NT - 1));
  const float4 v = *(const float4*)(w + i4);
  float f[4] = {v.x, v.y, v.z, v.w};
  ushort_t h[4], l[4];
#pragma unroll
  for (int q = 0; q < 4; ++q) {
    const int cc = c + q;
    float val = f[q];
    if (j == NT - 1 && cc == NT - 1) val = 1.0f;
    val = (cc >= j) ? val : 0.f;
    h[q] = f2bf_rtne(val);
    l[q] = f2bf_rtne(val - bf2f(h[q]));
  }
  *(uint2*)(UMh + i4) = make_uint2((unsigned)h[0] | ((unsigned)h[1] << 16),
                                   (unsigned)h[2] | ((unsigned)h[3] << 16));
  *(uint2*)(UMl + i4) = make_uint2((unsigned)l[0] | ((unsigned)l[1] << 16),
                                   (unsigned)l[2] | ((unsigned)l[3] << 16));
}

// =================== MFMA staging helpers (BK=32, stride 40) ===================

__device__ __forceinline__ void stage_f32ld(const float* __restrict__ src,
                                            int rb, int kb, int t, int ld,
                                            ushort_t* __restrict__ Hd,
                                            ushort_t* __restrict__ Ld) {
  const int r0 = t >> 3;
  const int seg = (t & 7) * 4;
#pragma unroll
  for (int p = 0; p < 4; ++p) {
    const int row = r0 + p * 32;
    const float4 v = *(const float4*)(src + (size_t)(rb + row) * ld + kb + seg);
    const float f[4] = {v.x, v.y, v.z, v.w};
    ushort_t h[4], l[4];
#pragma unroll
    for (int q = 0; q < 4; ++q) {
      h[q] = f2bf_rtne(f[q]);
      l[q] = f2bf_rtne(f[q] - bf2f(h[q]));
    }
    const int o = row * 40 + seg;
    *(uint2*)(Hd + o) = make_uint2((unsigned)h[0] | ((unsigned)h[1] << 16),
                                   (unsigned)h[2] | ((unsigned)h[3] << 16));
    *(uint2*)(Ld + o) = make_uint2((unsigned)l[0] | ((unsigned)l[1] << 16),
                                   (unsigned)l[2] | ((unsigned)l[3] << 16));
  }
}

__device__ __forceinline__ void stage_pre(const ushort_t* __restrict__ H,
                                          const ushort_t* __restrict__ L,
                                          int rb, int kb, int t,
                                          ushort_t* __restrict__ Hd,
                                          ushort_t* __restrict__ Ld) {
  const int r0 = t >> 1;
  const int seg = (t & 1) << 4;
  const size_t g = (size_t)(rb + r0) * NT + kb + seg;
  const int o = r0 * 40 + seg;
  *(bf16x8*)(Hd + o) = *(const bf16x8*)(H + g);
  *(bf16x8*)(Hd + o + 8) = *(const bf16x8*)(H + g + 8);
  *(bf16x8*)(Ld + o) = *(const bf16x8*)(L + g);
  *(bf16x8*)(Ld + o + 8) = *(const bf16x8*)(L + g + 8);
}

// UM^T staging: Ahs[c][l] = UM[kb+l][mb+c]  (for wbuild A-operand)
__device__ __forceinline__ void stage_umT(const ushort_t* __restrict__ H,
                                          const ushort_t* __restrict__ L,
                                          int mb, int kb, int t,
                                          ushort_t* __restrict__ Hd,
                                          ushort_t* __restrict__ Ld) {
  const int l = t & 31;
  const int grp = t >> 5;                 // 8 groups x 16 cols
  const size_t g = (size_t)(kb + l) * NT + mb + grp * 16;
  ushort_t hv[16], lv[16];
  *(uint4*)hv = *(const uint4*)(H + g);
  *(uint4*)(hv + 8) = *(const uint4*)(H + g + 8);
  *(uint4*)lv = *(const uint4*)(L + g);
  *(uint4*)(lv + 8) = *(const uint4*)(L + g + 8);
  const int cb = grp * 16;
#pragma unroll
  for (int e = 0; e < 16; ++e) {
    Hd[(cb + e) * 40 + l] = hv[e];
    Ld[(cb + e) * 40 + l] = lv[e];
  }
}

// =================== MFMA fragment compute (shared pattern) ===================

#define MFMA_BLOCK(Ahs, Als, Bhs, Bls)                                          \
  {                                                                             \
    bf16x8 ah[4], al[4], bh[4], bl[4];                                          \
    _Pragma("unroll") for (int fm = 0; fm < 4; ++fm) {                          \
      const int o = (wm * 64 + fm * 16 + lrow) * 40 + lk * 8;                   \
      ah[fm] = *(const bf16x8*)(Ahs + o);                                       \
      al[fm] = *(const bf16x8*)(Als + o);                                       \
    }                                                                           \
    _Pragma("unroll") for (int fn = 0; fn < 4; ++fn) {                          \
      const int o = (wn * 64 + fn * 16 + lrow) * 40 + lk * 8;                   \
      bh[fn] = *(const bf16x8*)(Bhs + o);                                       \
      bl[fn] = *(const bf16x8*)(Bls + o);                                       \
    }                                                                           \
    _Pragma("unroll") for (int fm = 0; fm < 4; ++fm)                            \
      _Pragma("unroll") for (int fn = 0; fn < 4; ++fn) {                        \
        acc[fm][fn] = __builtin_amdgcn_mfma_f32_16x16x32_bf16(ah[fm], bh[fn], acc[fm][fn], 0, 0, 0); \
        acc[fm][fn] = __builtin_amdgcn_mfma_f32_16x16x32_bf16(ah[fm], bl[fn], acc[fm][fn], 0, 0, 0); \
        acc[fm][fn] = __builtin_amdgcn_mfma_f32_16x16x32_bf16(al[fm], bh[fn], acc[fm][fn], 0, 0, 0); \
      }                                                                         \
  }

#define MFMA_DECLS                                                              \
  const int t = threadIdx.x;                                                    \
  const int l = t & 63, w = t >> 6;                                             \
  const int wm = w >> 1, wn = w & 1;                                            \
  const int lrow = l & 15, lk = l >> 4;                                         \
  f32x4 acc[4][4];                                                              \
  _Pragma("unroll") for (int i = 0; i < 4; ++i)                                 \
    _Pragma("unroll") for (int j = 0; j < 4; ++j) {                             \
      acc[i][j][0] = 0.f; acc[i][j][1] = 0.f;                                   \
      acc[i][j][2] = 0.f; acc[i][j][3] = 0.f;                                   \
    }                                                                           \
  (void)l;

// =================== gram: S upper tiles = UM UM^T ===================

__global__ __launch_bounds__(256)
void gram_kernel(const ushort_t* __restrict__ UMh, const ushort_t* __restrict__ UMl,
                 float* __restrict__ S) {
  int rem = blockIdx.x, ti = 0;
  while (rem >= NT128 - ti) { rem -= NT128 - ti; ++ti; }
  const int tj = ti + rem;
  const int mb = ti * 128, nb = tj * 128;

  __shared__ ushort_t Ahs[128 * 40], Als[128 * 40], Bhs[128 * 40], Bls[128 * 40];
  MFMA_DECLS

  for (int kb = nb; kb < NT; kb += 32) {      // tri-skip: c >= max(i,j)
    __syncthreads();
    stage_pre(UMh, UMl, mb, kb, t, Ahs, Als);
    stage_pre(UMh, UMl, nb, kb, t, Bhs, Bls);
    __syncthreads();
    MFMA_BLOCK(Ahs, Als, Bhs, Bls)
  }

#pragma unroll
  for (int fm = 0; fm < 4; ++fm) {
    const int m0 = mb + wm * 64 + fm * 16 + lk * 4;
#pragma unroll
    for (int fn = 0; fn < 4; ++fn) {
      const int n = nb + wn * 64 + fn * 16 + lrow;
#pragma unroll
      for (int r = 0; r < 4; ++r)
        S[(size_t)(m0 + r) * NT + n] = acc[fm][fn][r];
    }
  }
}

// =================== tbase64: larft recurrence per 64-group ===================

__global__ __launch_bounds__(64)
void tbase64_kernel(const float* __restrict__ S, float* __restrict__ T,
                    float* __restrict__ Tt) {
  __shared__ float Tl[64][65];
  __shared__ float scol[64];
  const int g0 = blockIdx.x * 64;
  const int r = threadIdx.x;

  for (int j = 0; j < 64; ++j) {
    __syncthreads();
    scol[r] = S[(size_t)(g0 + j) * NT + g0 + r];   // row j (== col j, symmetric)
    __syncthreads();
    const float sjj = scol[j];
    const float bj = (sjj > 0.f) ? 2.0f / sjj : 0.f;
    float val;
    if (r == j) val = bj;
    else if (r > j) val = 0.f;
    else {
      float a = 0.f;
      for (int ll = r; ll < j; ++ll) a = fmaf(Tl[r][ll], scol[ll], a);
      val = -bj * a;
    }
    Tl[r][j] = val;
  }
  __syncthreads();
  for (int c = 0; c < 64; ++c) T[(size_t)(g0 + r) * NT + g0 + c] = Tl[r][c];
  for (int c = 0; c < 64; ++c) Tt[(size_t)(g0 + c) * NT + g0 + r] = Tl[r][c];
}

// =================== fp32 64x64 NT core (general ld) ===================

__device__ __forceinline__
void core64(const float* __restrict__ A, int lda,
            const float* __restrict__ B, int ldb,
            int K, float (&acc)[4][4]) {
  __shared__ float As[16][68];
  __shared__ float Bs[16][68];
  const int tid = threadIdx.x;
  const int tn = tid & 15, tm = tid >> 4;
  const int rowl = tid >> 2;
  const int kq = (tid & 3) << 2;

  for (int c = 0; c < K; c += 16) {
    {
      const float4 v = *(const float4*)(A + (size_t)rowl * lda + c + kq);
      As[kq + 0][rowl] = v.x; As[kq + 1][rowl] = v.y;
      As[kq + 2][rowl] = v.z; As[kq + 3][rowl] = v.w;
      const float4 u = *(const float4*)(B + (size_t)rowl * ldb + c + kq);
      Bs[kq + 0][rowl] = u.x; Bs[kq + 1][rowl] = u.y;
      Bs[kq + 2][rowl] = u.z; Bs[kq + 3][rowl] = u.w;
    }
    __syncthreads();
#pragma unroll
    for (int kk = 0; kk < 16; ++kk) {
      const float4 a4 = *(const float4*)&As[kk][tm * 4];
      const float4 b4 = *(const float4*)&Bs[kk][tn * 4];
      acc[0][0] = fmaf(a4.x, b4.x, acc[0][0]);
      acc[0][1] = fmaf(a4.x, b4.y, acc[0][1]);
      acc[0][2] = fmaf(a4.x, b4.z, acc[0][2]);
      acc[0][3] = fmaf(a4.x, b4.w, acc[0][3]);
      acc[1][0] = fmaf(a4.y, b4.x, acc[1][0]);
      acc[1][1] = fmaf(a4.y, b4.y, acc[1][1]);
      acc[1][2] = fmaf(a4.y, b4.z, acc[1][2]);
      acc[1][3] = fmaf(a4.y, b4.w, acc[1][3]);
      acc[2][0] = fmaf(a4.z, b4.x, acc[2][0]);
      acc[2][1] = fmaf(a4.z, b4.y, acc[2][1]);
      acc[2][2] = fmaf(a4.z, b4.z, acc[2][2]);
      acc[2][3] = fmaf(a4.z, b4.w, acc[2][3]);
      acc[3][0] = fmaf(a4.w, b4.x, acc[3][0]);
      acc[3][1] = fmaf(a4.w, b4.y, acc[3][1]);
      acc[3][2] = fmaf(a4.w, b4.z, acc[3][2]);
      acc[3][3] = fmaf(a4.w, b4.w, acc[3][3]);
    }
    __syncthreads();
  }
}

// step1: P[q][p] = sum_l Tt[b0+q][b0+l] * S[a0+p][b0+l]   (P in S lower-left carve)
__global__ __launch_bounds__(256)
void tmerge1_kernel(const float* __restrict__ Tt, const float* __restrict__ S,
                    float* __restrict__ Scv, int k) {
  const int tpk = k >> 6;
  const int tiles = tpk * tpk;
  const int m = blockIdx.x / tiles;
  const int rest = blockIdx.x % tiles;
  const int mb = (rest / tpk) * 64;   // q
  const int nb = (rest % tpk) * 64;   // p
  const int a0 = 2 * k * m, b0 = a0 + k;
  float acc[4][4] = {};
  core64(Tt + (size_t)(b0 + mb) * NT + b0, NT,
         S + (size_t)(a0 + nb) * NT + b0, NT, k, acc);
  const int tn = threadIdx.x & 15, tm = threadIdx.x >> 4;
#pragma unroll
  for (int i = 0; i < 4; ++i)
#pragma unroll
    for (int jj = 0; jj < 4; ++jj)
      Scv[(size_t)(1024 + mb + tm * 4 + i) * NT + (size_t)m * k + nb + tn * 4 + jj] = acc[i][jj];
}

// step2: Tt[b0+q][a0+r] = T[a0+r][b0+q] = -sum_p P[q][p] * T[a0+r][a0+p]
__global__ __launch_bounds__(256)
void tmerge2_kernel(const float* __restrict__ Scv, float* __restrict__ T,
                    float* __restrict__ Tt, int k) {
  const int tpk = k >> 6;
  const int tiles = tpk * tpk;
  const int m = blockIdx.x / tiles;
  const int rest = blockIdx.x % tiles;
  const int mb = (rest / tpk) * 64;   // q
  const int nb = (rest % tpk) * 64;   // r
  const int a0 = 2 * k * m, b0 = a0 + k;
  float acc[4][4] = {};
  core64(Scv + (size_t)(1024 + mb) * NT + (size_t)m * k, NT,
         T + (size_t)(a0 + nb) * NT + a0, NT, k, acc);
  const int tn = threadIdx.x & 15, tm = threadIdx.x >> 4;
#pragma unroll
  for (int i = 0; i < 4; ++i) {
    const int q = mb + tm * 4 + i;
#pragma unroll
    for (int jj = 0; jj < 4; ++jj) {
      const int r = nb + tn * 4 + jj;
      const float v = -acc[i][jj];
      Tt[(size_t)(b0 + q) * NT + a0 + r] = v;
      T[(size_t)(a0 + r) * NT + b0 + q] = v;
    }
  }
}

// MFMA variants for k >= 512 (fp32 on-fly both operands)
__global__ __launch_bounds__(256)
void tmerge1m_kernel(const float* __restrict__ Tt, const float* __restrict__ S,
                     float* __restrict__ Scv, int k) {
  const int tpk = k >> 7;
  const int tiles = tpk * tpk;
  const int m = blockIdx.x / tiles;
  const int rest = blockIdx.x % tiles;
  const int mb = (rest / tpk) * 128;
  const int nb = (rest % tpk) * 128;
  const int a0 = 2 * k * m, b0 = a0 + k;

  __shared__ ushort_t Ahs[128 * 40], Als[128 * 40], Bhs[128 * 40], Bls[128 * 40];
  MFMA_DECLS

  for (int kb = 0; kb < k; kb += 32) {
    __syncthreads();
    stage_f32ld(Tt + (size_t)b0 * NT + b0, mb, kb, t, NT, Ahs, Als);
    stage_f32ld(S + (size_t)a0 * NT + b0, nb, kb, t, NT, Bhs, Bls);
    __syncthreads();
    MFMA_BLOCK(Ahs, Als, Bhs, Bls)
  }

#pragma unroll
  for (int fm = 0; fm < 4; ++fm) {
    const int m0 = mb + wm * 64 + fm * 16 + lk * 4;
#pragma unroll
    for (int fn = 0; fn < 4; ++fn) {
      const int n = nb + wn * 64 + fn * 16 + lrow;
#pragma unroll
      for (int r = 0; r < 4; ++r)
        Scv[(size_t)(1024 + m0 + r) * NT + (size_t)m * k + n] = acc[fm][fn][r];
    }
  }
}

__global__ __launch_bounds__(256)
void tmerge2m_kernel(const float* __restrict__ Scv, float* __restrict__ T,
                     float* __restrict__ Tt, int k) {
  const int tpk = k >> 7;
  const int tiles = tpk * tpk;
  const int m = blockIdx.x / tiles;
  const int rest = blockIdx.x % tiles;
  const int mb = (rest / tpk) * 128;
  const int nb = (rest % tpk) * 128;
  const int a0 = 2 * k * m, b0 = a0 + k;

  __shared__ ushort_t Ahs[128 * 40], Als[128 * 40], Bhs[128 * 40], Bls[128 * 40];
  MFMA_DECLS

  for (int kb = 0; kb < k; kb += 32) {
    __syncthreads();
    stage_f32ld(Scv + (size_t)1024 * NT + (size_t)m * k, mb, kb, t, NT, Ahs, Als);
    stage_f32ld(T + (size_t)a0 * NT + a0, nb, kb, t, NT, Bhs, Bls);
    __syncthreads();
    MFMA_BLOCK(Ahs, Als, Bhs, Bls)
  }

#pragma unroll
  for (int fm = 0; fm < 4; ++fm) {
    const int q0 = mb + wm * 64 + fm * 16 + lk * 4;
#pragma unroll
    for (int fn = 0; fn < 4; ++fn) {
      const int r = nb + wn * 64 + fn * 16 + lrow;
#pragma unroll
      for (int e = 0; e < 4; ++e) {
        const float v = -acc[fm][fn][e];
        Tt[(size_t)(b0 + q0 + e) * NT + a0 + r] = v;
        T[(size_t)(a0 + r) * NT + b0 + q0 + e] = v;
      }
    }
  }
}

// =================== wbuild: W[c][j] = sum_l UM[l][c] T[l][j] ===================

__global__ __launch_bounds__(256)
void wbuild_kernel(const ushort_t* __restrict__ UMh, const ushort_t* __restrict__ UMl,
                   const float* __restrict__ Tt,
                   ushort_t* __restrict__ Wh, ushort_t* __restrict__ Wl) {
  const int mb = (blockIdx.x >> 4) * 128;   // c
  const int nb = (blockIdx.x & 15) * 128;   // j
  const int kend = (mb < nb ? mb : nb) + 128;   // l <= min(c,j)

  __shared__ ushort_t Ahs[128 * 40], Als[128 * 40], Bhs[128 * 40], Bls[128 * 40];
  MFMA_DECLS

  for (int kb = 0; kb < kend; kb += 32) {
    __syncthreads();
    stage_umT(UMh, UMl, mb, kb, t, Ahs, Als);
    stage_f32ld(Tt, nb, kb, t, NT, Bhs, Bls);
    __syncthreads();
    MFMA_BLOCK(Ahs, Als, Bhs, Bls)
  }

#pragma unroll
  for (int fm = 0; fm < 4; ++fm) {
    const int m0 = mb + wm * 64 + fm * 16 + lk * 4;
#pragma unroll
    for (int fn = 0; fn < 4; ++fn) {
      const int n = nb + wn * 64 + fn * 16 + lrow;
#pragma unroll
      for (int r = 0; r < 4; ++r) {
        const size_t idx = (size_t)(m0 + r) * NT + n;
        const float f = acc[fm][fn][r];
        const ushort_t h = f2bf_rtne(f);
        Wh[idx] = h;
        Wl[idx] = f2bf_rtne(f - bf2f(h));
      }
    }
  }
}

// =================== application GEMMs (r6-proven, BK=32) ===================

template <int ASRC, int EP>
__global__ __launch_bounds__(256)
void gemm_bf_kernel(const float* __restrict__ Af,
                    const ushort_t* __restrict__ Ahg, const ushort_t* __restrict__ Alg,
                    const ushort_t* __restrict__ Bhg, const ushort_t* __restrict__ Blg,
                    const float* __restrict__ X, float* __restrict__ Cf,
                    ushort_t* __restrict__ Ch, ushort_t* __restrict__ Cl,
                    int tri) {
  __shared__ ushort_t Ahs[128 * 40], Als[128 * 40], Bhs[128 * 40], Bls[128 * 40];
  int bid = blockIdx.x;
  const int nwg = gridDim.x;
  if ((nwg & 7) == 0) {
    const int q = nwg >> 3;
    bid = (bid & 7) * q + (bid >> 3);
  }
  const int mb = (bid / NT128) * 128;
  const int nb = (bid % NT128) * 128;
  const int k0 = tri ? nb : 0;

  MFMA_DECLS

  for (int kb = k0; kb < NT; kb += 32) {
    __syncthreads();
    if (ASRC) stage_f32ld(Af, mb, kb, t, NT, Ahs, Als);
    else      stage_pre(Ahg, Alg, mb, kb, t, Ahs, Als);
    stage_pre(Bhg, Blg, nb, kb, t, Bhs, Bls);
    __syncthreads();
    MFMA_BLOCK(Ahs, Als, Bhs, Bls)
  }

#pragma unroll
  for (int fm = 0; fm < 4; ++fm) {
    const int m0 = mb + wm * 64 + fm * 16 + lk * 4;
#pragma unroll
    for (int fn = 0; fn < 4; ++fn) {
      const int n = nb + wn * 64 + fn * 16 + lrow;
#pragma unroll
      for (int r = 0; r < 4; ++r) {
        const size_t idx = (size_t)(m0 + r) * NT + n;
        const float f = acc[fm][fn][r];
        if (EP == 1) {
          Cf[idx] = X[idx] - f;
        } else {
          const ushort_t h = f2bf_rtne(f);
          Ch[idx] = h;
          Cl[idx] = f2bf_rtne(f - bf2f(h));
        }
      }
    }
  }
}

// =================== fallback sweep (round-2, proven) ===================

#define NRF 32
#define VCF 2
#define KGF 8
#define WPBF 4
#define NGRAMF ((KGF * (KGF + 1)) / 2)
#define NREDF (NGRAMF + KGF * VCF)

__device__ __forceinline__ void accum_group_f(const float (&u)[KGF],
                                              const float (&hr)[VCF],
                                              float (&red)[NREDF]) {
#pragma unroll
  for (int j = 0; j < KGF; ++j) {
#pragma unroll
    for (int l = 0; l <= j; ++l)
      red[(j * (j + 1)) / 2 + l] = fmaf(u[j], u[l], red[(j * (j + 1)) / 2 + l]);
#pragma unroll
    for (int c = 0; c < VCF; ++c)
      red[NGRAMF + j * VCF + c] = fmaf(u[j], hr[c], red[NGRAMF + j * VCF + c]);
  }
}

__global__ __launch_bounds__(256, 2)
void fallback_sweep_kernel(const float* __restrict__ x,
                           const float* __restrict__ w,
                           float* __restrict__ out) {
  const int lane = threadIdx.x & 63;
  const int wave = threadIdx.x >> 6;
  const int gw = blockIdx.x * WPBF + wave;
  const int col0 = gw * VCF;
  float h[NRF][VCF];
#pragma unroll
  for (int k = 0; k < NRF; ++k) {
    const int r = lane + 64 * k;
#pragma unroll
    for (int c = 0; c < VCF; ++c) h[k][c] = x[(size_t)(col0 + c) * NT + r];
  }
  for (int i0 = NT - KGF; i0 >= 0; i0 -= KGF) {
    const int ks = i0 >> 6;
    const float* wb = w + (size_t)i0 * NT;
    float red[NREDF];
#pragma unroll
    for (int t = 0; t < NREDF; ++t) red[t] = 0.f;
#pragma unroll
    for (int k = 0; k < NRF; ++k) {
      const int r = lane + 64 * k;
      if (k > ks) {
        float u[KGF];
#pragma unroll
        for (int j = 0; j < KGF; ++j) u[j] = wb[(size_t)j * NT + r];
        accum_group_f(u, h[k], red);
      } else if (k == ks) {
        float u[KGF];
#pragma unroll
        for (int j = 0; j < KGF; ++j) {
          float tt = wb[(size_t)j * NT + r];
          u[j] = (r >= i0 + j) ? tt : 0.f;
        }
        if (i0 == NT - KGF && r == NT - 1) u[KGF - 1] = 1.0f;
        accum_group_f(u, h[k], red);
      }
    }
#pragma unroll
    for (int m = 1; m < 64; m <<= 1)
#pragma unroll
      for (int t = 0; t < NREDF; ++t) red[t] += __shfl_xor(red[t], m, 64);
    float beta[KGF];
#pragma unroll
    for (int j = 0; j < KGF; ++j) {
      const float n2 = red[(j * (j + 1)) / 2 + j];
      beta[j] = (n2 > 0.f) ? 2.0f / n2 : 0.f;
    }
    float T[KGF][KGF];
#pragma unroll
    for (int j = 0; j < KGF; ++j) {
      T[j][j] = beta[j];
#pragma unroll
      for (int r0 = 0; r0 < j; ++r0) {
        float acc = 0.f;
#pragma unroll
        for (int l = r0; l < j; ++l)
          acc = fmaf(T[r0][l], red[(j * (j + 1)) / 2 + l], acc);
        T[r0][j] = -beta[j] * acc;
      }
    }
    float z[KGF][VCF];
#pragma unroll
    for (int j = 0; j < KGF; ++j)
#pragma unroll
      for (int c = 0; c < VCF; ++c) {
        float acc = 0.f;
#pragma unroll
        for (int l = j; l < KGF; ++l)
          acc = fmaf(T[j][l], red[NGRAMF + l * VCF + c], acc);
        z[j][c] = acc;
      }
#pragma unroll
    for (int k = 0; k < NRF; ++k) {
      const int r = lane + 64 * k;
      if (k >= ks) {
        float u[KGF];
#pragma unroll
        for (int j = 0; j < KGF; ++j) {
          float tt = wb[(size_t)j * NT + r];
          u[j] = (k > ks || r >= i0 + j) ? tt : 0.f;
        }
        if (i0 == NT - KGF && r == NT - 1) u[KGF - 1] = 1.0f;
#pragma unroll
        for (int c = 0; c < VCF; ++c) {
          float acc = h[k][c];
#pragma unroll
          for (int j = 0; j < KGF; ++j) acc = fmaf(-u[j], z[j][c], acc);
          h[k][c] = acc;
        }
      }
    }
  }
#pragma unroll
  for (int k = 0; k < NRF; ++k) {
    const int r = lane + 64 * k;
#pragma unroll
    for (int c = 0; c < VCF; ++c)
      out[(size_t)(col0 + c) * NT + r] = h[k][c];
  }
}

// =================== launch ===================

extern "C" void kernel_launch(void* const* d_in, const int* in_sizes, int n_in,
                              void* d_out, int out_size, void* d_ws, size_t ws_size,
                              hipStream_t stream) {
  const float* x = (const float*)d_in[0];
  const float* w = (const float*)d_in[1];
  float* out = (float*)d_out;
  const int Bsz = in_sizes[0] / NT;         // 4096

  const size_t NW = (size_t)NT * NT;        // 4M floats
  float* ws = (float*)d_ws;

  float* S  = ws;                           // [0,4M)  (P carve: rows 1024+, cols <1024)
  float* T  = ws + NW;                      // [4,8M)
  float* Tt = ws + 2 * NW;                  // [8,12M)
  ushort_t* UMh = (ushort_t*)(ws + 3 * NW); // [12,14M)
  ushort_t* UMl = UMh + NW;                 // [14,16M)
  ushort_t* Wh = (ushort_t*)ws;             // [0,2M)  after merges (S dead)
  ushort_t* Wl = (ushort_t*)(ws + NW / 2);  // [2,4M)
  ushort_t* A1h = (ushort_t*)(ws + NW);     // [4,8M)  after wbuild (T dead)
  ushort_t* A1l = (ushort_t*)(ws + 2 * NW); // [8,12M) after wbuild (Tt dead)

  const size_t need = 4 * NW * sizeof(float);   // 64 MB

  if (ws_size < need || (Bsz % 128) != 0) {
    fallback_sweep_kernel<<<Bsz / (VCF * WPBF), 256, 0, stream>>>(x, w, out);
    return;
  }

  prep_split_kernel<<<(int)(NW / 1024), 256, 0, stream>>>(w, UMh, UMl);
  gram_kernel<<<NT128 * (NT128 + 1) / 2, 256, 0, stream>>>(UMh, UMl, S);   // 136
  hipMemsetAsync(T, 0, 2 * NW * sizeof(float), stream);                    // T + Tt
  tbase64_kernel<<<32, 64, 0, stream>>>(S, T, Tt);

  for (int k = 64; k <= 1024; k <<= 1) {
    const int mm = NT / (2 * k);
    if (k <= 256) {
      const int grid = mm * (k >> 6) * (k >> 6);
      tmerge1_kernel<<<grid, 256, 0, stream>>>(Tt, S, S, k);
      tmerge2_kernel<<<grid, 256, 0, stream>>>(S, T, Tt, k);
    } else {
      const int grid = mm * (k >> 7) * (k >> 7);
      tmerge1m_kernel<<<grid, 256, 0, stream>>>(Tt, S, S, k);
      tmerge2m_kernel<<<grid, 256, 0, stream>>>(S, T, Tt, k);
    }
  }

  wbuild_kernel<<<NT128 * NT128, 256, 0, stream>>>(UMh, UMl, Tt, Wh, Wl);

  const int grid = (Bsz / 128) * NT128;     // 512
  gemm_bf_kernel<1, 2><<<grid, 256, 0, stream>>>(
      x, nullptr, nullptr, UMh, UMl, nullptr, nullptr, A1h, A1l, 1);
  gemm_bf_kernel<0, 1><<<grid, 256, 0, stream>>>(
      nullptr, A1h, A1l, Wh, Wl, x, out, nullptr, nullptr, 0);
}

// Round 9
// 601.972 us; speedup vs baseline: 1.4268x; 1.2482x over previous
//
#include <hip/hip_runtime.h>

// OrthogonalTransform via gram + T-matrix (compact WY) + MFMA application.
// out = X Q^T, Q = I - V T V^T, V rows = triu(weight) (U[-1,-1]=1).
// T^-1 + T^-T = S = V V^T; merge T_{a∪b} off-diag = -Ta S_ab Tb.
// W = V T;  out = X - (X V^T) W^T.
//
// ws (floats, 16M = 64 MB):
//   [0,4M)   S (upper tiles; lower-left quadrant = P scratch) -> Wh/Wl
//   [4,8M)   T  (lower-left dead = P slice1 @k=1024)          -> A1h
//   [8,12M)  Tt                                               -> A1l
//   [12,16M) UMh + UMl
// d_out (8M floats) = staged scratch: gram partials -> t2 partials ->
//   wbuild partials -> Xh/Xl (each dead before next use), then final out.

#define NT 2048
#define NT128 16
#define LSTR 48            // LDS row stride in shorts (96B): 4-way banks

typedef __attribute__((ext_vector_type(8))) short bf16x8;
typedef __attribute__((ext_vector_type(4))) float f32x4;
typedef unsigned short ushort_t;

__device__ __forceinline__ ushort_t f2bf_rtne(float f) {
  unsigned u = __builtin_bit_cast(unsigned, f);
  u += 0x7FFFu + ((u >> 16) & 1u);
  return (ushort_t)(u >> 16);
}
__device__ __forceinline__ float bf2f(ushort_t h) {
  return __builtin_bit_cast(float, (unsigned)h << 16);
}

// =================== prep kernels ===================

__global__ __launch_bounds__(256)
void prep_split_kernel(const float* __restrict__ w,
                       ushort_t* __restrict__ UMh, ushort_t* __restrict__ UMl) {
  const size_t i4 = ((size_t)blockIdx.x * 256 + threadIdx.x) * 4;
  const int j = (int)(i4 >> 11);
  const int c = (int)(i4 & (NT - 1));
  const float4 v = *(const float4*)(w + i4);
  float f[4] = {v.x, v.y, v.z, v.w};
  ushort_t h[4], l[4];
#pragma unroll
  for (int q = 0; q < 4; ++q) {
    const int cc = c + q;
    float val = f[q];
    if (j == NT - 1 && cc == NT - 1) val = 1.0f;
    val = (cc >= j) ? val : 0.f;
    h[q] = f2bf_rtne(val);
    l[q] = f2bf_rtne(val - bf2f(h[q]));
  }
  *(uint2*)(UMh + i4) = make_uint2((unsigned)h[0] | ((unsigned)h[1] << 16),
                                   (unsigned)h[2] | ((unsigned)h[3] << 16));
  *(uint2*)(UMl + i4) = make_uint2((unsigned)l[0] | ((unsigned)l[1] << 16),
                                   (unsigned)l[2] | ((unsigned)l[3] << 16));
}

__global__ __launch_bounds__(256)
void prep_x_kernel(const float* __restrict__ x,
                   ushort_t* __restrict__ Xh, ushort_t* __restrict__ Xl) {
  const size_t i4 = ((size_t)blockIdx.x * 256 + threadIdx.x) * 4;
  const float4 v = *(const float4*)(x + i4);
  const float f[4] = {v.x, v.y, v.z, v.w};
  ushort_t h[4], l[4];
#pragma unroll
  for (int q = 0; q < 4; ++q) {
    h[q] = f2bf_rtne(f[q]);
    l[q] = f2bf_rtne(f[q] - bf2f(h[q]));
  }
  *(uint2*)(Xh + i4) = make_uint2((unsigned)h[0] | ((unsigned)h[1] << 16),
                                  (unsigned)h[2] | ((unsigned)h[3] << 16));
  *(uint2*)(Xl + i4) = make_uint2((unsigned)l[0] | ((unsigned)l[1] << 16),
                                  (unsigned)l[2] | ((unsigned)l[3] << 16));
}

// =================== MFMA staging (stride LSTR) ===================

__device__ __forceinline__ void stage_f32ld(const float* __restrict__ src,
                                            int rb, int kb, int t, int ld,
                                            ushort_t* __restrict__ Hd,
                                            ushort_t* __restrict__ Ld) {
  const int r0 = t >> 3;
  const int seg = (t & 7) * 4;
#pragma unroll
  for (int p = 0; p < 4; ++p) {
    const int row = r0 + p * 32;
    const float4 v = *(const float4*)(src + (size_t)(rb + row) * ld + kb + seg);
    const float f[4] = {v.x, v.y, v.z, v.w};
    ushort_t h[4], l[4];
#pragma unroll
    for (int q = 0; q < 4; ++q) {
      h[q] = f2bf_rtne(f[q]);
      l[q] = f2bf_rtne(f[q] - bf2f(h[q]));
    }
    const int o = row * LSTR + seg;
    *(uint2*)(Hd + o) = make_uint2((unsigned)h[0] | ((unsigned)h[1] << 16),
                                   (unsigned)h[2] | ((unsigned)h[3] << 16));
    *(uint2*)(Ld + o) = make_uint2((unsigned)l[0] | ((unsigned)l[1] << 16),
                                   (unsigned)l[2] | ((unsigned)l[3] << 16));
  }
}

// A = sum of two fp32 partial slices
__device__ __forceinline__ void stage_a2(const float* __restrict__ A0,
                                         const float* __restrict__ A1,
                                         int rb, int kb, int t, int ld,
                                         ushort_t* __restrict__ Hd,
                                         ushort_t* __restrict__ Ld) {
  const int r0 = t >> 3;
  const int seg = (t & 7) * 4;
#pragma unroll
  for (int p = 0; p < 4; ++p) {
    const int row = r0 + p * 32;
    const size_t g = (size_t)(rb + row) * ld + kb + seg;
    const float4 v0 = *(const float4*)(A0 + g);
    const float4 v1 = *(const float4*)(A1 + g);
    const float f[4] = {v0.x + v1.x, v0.y + v1.y, v0.z + v1.z, v0.w + v1.w};
    ushort_t h[4], l[4];
#pragma unroll
    for (int q = 0; q < 4; ++q) {
      h[q] = f2bf_rtne(f[q]);
      l[q] = f2bf_rtne(f[q] - bf2f(h[q]));
    }
    const int o = row * LSTR + seg;
    *(uint2*)(Hd + o) = make_uint2((unsigned)h[0] | ((unsigned)h[1] << 16),
                                   (unsigned)h[2] | ((unsigned)h[3] << 16));
    *(uint2*)(Ld + o) = make_uint2((unsigned)l[0] | ((unsigned)l[1] << 16),
                                   (unsigned)l[2] | ((unsigned)l[3] << 16));
  }
}

__device__ __forceinline__ void stage_pre(const ushort_t* __restrict__ H,
                                          const ushort_t* __restrict__ L,
                                          int rb, int kb, int t,
                                          ushort_t* __restrict__ Hd,
                                          ushort_t* __restrict__ Ld) {
  const int r0 = t >> 1;
  const int seg = (t & 1) << 4;
  const size_t g = (size_t)(rb + r0) * NT + kb + seg;
  const int o = r0 * LSTR + seg;
  *(bf16x8*)(Hd + o) = *(const bf16x8*)(H + g);
  *(bf16x8*)(Hd + o + 8) = *(const bf16x8*)(H + g + 8);
  *(bf16x8*)(Ld + o) = *(const bf16x8*)(L + g);
  *(bf16x8*)(Ld + o + 8) = *(const bf16x8*)(L + g + 8);
}

// UM^T staging: Hd[c][l] = UM[kb+l][mb+c]
__device__ __forceinline__ void stage_umT(const ushort_t* __restrict__ H,
                                          const ushort_t* __restrict__ L,
                                          int mb, int kb, int t,
                                          ushort_t* __restrict__ Hd,
                                          ushort_t* __restrict__ Ld) {
  const int l = t & 31;
  const int grp = t >> 5;
  const size_t g = (size_t)(kb + l) * NT + mb + grp * 16;
  ushort_t hv[16], lv[16];
  *(uint4*)hv = *(const uint4*)(H + g);
  *(uint4*)(hv + 8) = *(const uint4*)(H + g + 8);
  *(uint4*)lv = *(const uint4*)(L + g);
  *(uint4*)(lv + 8) = *(const uint4*)(L + g + 8);
  const int cb = grp * 16;
#pragma unroll
  for (int e = 0; e < 16; ++e) {
    Hd[(cb + e) * LSTR + l] = hv[e];
    Ld[(cb + e) * LSTR + l] = lv[e];
  }
}

#define MFMA_BLOCK(Ahs, Als, Bhs, Bls)                                          \
  {                                                                             \
    bf16x8 ah[4], al[4], bh[4], bl[4];                                          \
    _Pragma("unroll") for (int fm = 0; fm < 4; ++fm) {                          \
      const int o = (wm * 64 + fm * 16 + lrow) * LSTR + lk * 8;                 \
      ah[fm] = *(const bf16x8*)(Ahs + o);                                       \
      al[fm] = *(const bf16x8*)(Als + o);                                       \
    }                                                                           \
    _Pragma("unroll") for (int fn = 0; fn < 4; ++fn) {                          \
      const int o = (wn * 64 + fn * 16 + lrow) * LSTR + lk * 8;                 \
      bh[fn] = *(const bf16x8*)(Bhs + o);                                       \
      bl[fn] = *(const bf16x8*)(Bls + o);                                       \
    }                                                                           \
    _Pragma("unroll") for (int fm = 0; fm < 4; ++fm)                            \
      _Pragma("unroll") for (int fn = 0; fn < 4; ++fn) {                        \
        acc[fm][fn] = __builtin_amdgcn_mfma_f32_16x16x32_bf16(ah[fm], bh[fn], acc[fm][fn], 0, 0, 0); \
        acc[fm][fn] = __builtin_amdgcn_mfma_f32_16x16x32_bf16(ah[fm], bl[fn], acc[fm][fn], 0, 0, 0); \
        acc[fm][fn] = __builtin_amdgcn_mfma_f32_16x16x32_bf16(al[fm], bh[fn], acc[fm][fn], 0, 0, 0); \
      }                                                                         \
  }

#define MFMA_DECLS                                                              \
  const int t = threadIdx.x;                                                    \
  const int l = t & 63, w = t >> 6;                                             \
  const int wm = w >> 1, wn = w & 1;                                            \
  const int lrow = l & 15, lk = l >> 4;                                         \
  f32x4 acc[4][4];                                                              \
  _Pragma("unroll") for (int i = 0; i < 4; ++i)                                 \
    _Pragma("unroll") for (int j = 0; j < 4; ++j) {                             \
      acc[i][j][0] = 0.f; acc[i][j][1] = 0.f;                                   \
      acc[i][j][2] = 0.f; acc[i][j][3] = 0.f;                                   \
    }                                                                           \
  (void)l;

// =================== gram: split-K (SK=3) + reduce ===================

__global__ __launch_bounds__(256)
void gram_sk_kernel(const ushort_t* __restrict__ UMh, const ushort_t* __restrict__ UMl,
                    float* __restrict__ Pg) {
  const int b = blockIdx.x;
  const int tile = b / 3, s = b % 3;
  int rem = tile, ti = 0;
  while (rem >= NT128 - ti) { rem -= NT128 - ti; ++ti; }
  const int tj = ti + rem;
  const int mb = ti * 128, nb = tj * 128;
  const int K = NT - nb;                        // tri-skip: c >= nb
  const int clen = ((K + 2) / 3 + 31) & ~31;
  int cbeg = nb + s * clen, cend = cbeg + clen;
  if (cbeg > NT) cbeg = NT;
  if (cend > NT) cend = NT;

  __shared__ ushort_t Ahs[128 * LSTR], Als[128 * LSTR], Bhs[128 * LSTR], Bls[128 * LSTR];
  MFMA_DECLS

  for (int kb = cbeg; kb < cend; kb += 32) {
    __syncthreads();
    stage_pre(UMh, UMl, mb, kb, t, Ahs, Als);
    stage_pre(UMh, UMl, nb, kb, t, Bhs, Bls);
    __syncthreads();
    MFMA_BLOCK(Ahs, Als, Bhs, Bls)
  }

  float* outp = Pg + (size_t)b * 16384;
#pragma unroll
  for (int fm = 0; fm < 4; ++fm) {
    const int rl = wm * 64 + fm * 16 + lk * 4;
#pragma unroll
    for (int fn = 0; fn < 4; ++fn) {
      const int cl = wn * 64 + fn * 16 + lrow;
#pragma unroll
      for (int r = 0; r < 4; ++r)
        outp[(rl + r) * 128 + cl] = acc[fm][fn][r];
    }
  }
}

__global__ __launch_bounds__(256)
void greduce_kernel(const float* __restrict__ Pg, float* __restrict__ S) {
  const size_t idx4 = ((size_t)blockIdx.x * 256 + threadIdx.x) * 4;
  const int tile = (int)(idx4 >> 14);
  const int off = (int)(idx4 & 16383);
  int rem = tile, ti = 0;
  while (rem >= NT128 - ti) { rem -= NT128 - ti; ++ti; }
  const int tj = ti + rem;
  const float* p = Pg + (size_t)tile * 3 * 16384 + off;
  float4 a = *(const float4*)p;
  const float4 b2 = *(const float4*)(p + 16384);
  const float4 c2 = *(const float4*)(p + 32768);
  a.x += b2.x + c2.x; a.y += b2.y + c2.y; a.z += b2.z + c2.z; a.w += b2.w + c2.w;
  *(float4*)(S + (size_t)(ti * 128 + off / 128) * NT + tj * 128 + (off & 127)) = a;
}

// =================== tbase64 (LDS-preloaded S block) ===================

__global__ __launch_bounds__(64)
void tbase64_kernel(const float* __restrict__ S, float* __restrict__ T,
                    float* __restrict__ Tt) {
  __shared__ float Tl[64][65];
  __shared__ float Sb[64][65];
  const int g0 = blockIdx.x * 64;
  const int r = threadIdx.x;
  for (int i = 0; i < 64; ++i) Sb[i][r] = S[(size_t)(g0 + i) * NT + g0 + r];
  __syncthreads();

  for (int j = 0; j < 64; ++j) {
    const float sjj = Sb[j][j];
    const float bj = (sjj > 0.f) ? 2.0f / sjj : 0.f;
    float val;
    if (r == j) val = bj;
    else if (r > j) val = 0.f;
    else {
      float a = 0.f;
      for (int ll = r; ll < j; ++ll) a = fmaf(Tl[r][ll], Sb[j][ll], a);
      val = -bj * a;
    }
    Tl[r][j] = val;
    __syncthreads();
  }
  for (int c = 0; c < 64; ++c) T[(size_t)(g0 + r) * NT + g0 + c] = Tl[r][c];
  for (int c = 0; c < 64; ++c) Tt[(size_t)(g0 + c) * NT + g0 + r] = Tl[r][c];
}

// =================== fp32 64x64 NT core ===================

__device__ __forceinline__
void core64(const float* __restrict__ A, int lda,
            const float* __restrict__ B, int ldb,
            int K, float (&acc)[4][4]) {
  __shared__ float As[16][68];
  __shared__ float Bs[16][68];
  const int tid = threadIdx.x;
  const int tn = tid & 15, tm = tid >> 4;
  const int rowl = tid >> 2;
  const int kq = (tid & 3) << 2;

  for (int c = 0; c < K; c += 16) {
    {
      const float4 v = *(const float4*)(A + (size_t)rowl * lda + c + kq);
      As[kq + 0][rowl] = v.x; As[kq + 1][rowl] = v.y;
      As[kq + 2][rowl] = v.z; As[kq + 3][rowl] = v.w;
      const float4 u = *(const float4*)(B + (size_t)rowl * ldb + c + kq);
      Bs[kq + 0][rowl] = u.x; Bs[kq + 1][rowl] = u.y;
      Bs[kq + 2][rowl] = u.z; Bs[kq + 3][rowl] = u.w;
    }
    __syncthreads();
#pragma unroll
    for (int kk = 0; kk < 16; ++kk) {
      const float4 a4 = *(const float4*)&As[kk][tm * 4];
      const float4 b4 = *(const float4*)&Bs[kk][tn * 4];
      acc[0][0] = fmaf(a4.x, b4.x, acc[0][0]);
      acc[0][1] = fmaf(a4.x, b4.y, acc[0][1]);
      acc[0][2] = fmaf(a4.x, b4.z, acc[0][2]);
      acc[0][3] = fmaf(a4.x, b4.w, acc[0][3]);
      acc[1][0] = fmaf(a4.y, b4.x, acc[1][0]);
      acc[1][1] = fmaf(a4.y, b4.y, acc[1][1]);
      acc[1][2] = fmaf(a4.y, b4.z, acc[1][2]);
      acc[1][3] = fmaf(a4.y, b4.w, acc[1][3]);
      acc[2][0] = fmaf(a4.z, b4.x, acc[2][0]);
      acc[2][1] = fmaf(a4.z, b4.y, acc[2][1]);
      acc[2][2] = fmaf(a4.z, b4.z, acc[2][2]);
      acc[2][3] = fmaf(a4.z, b4.w, acc[2][3]);
      acc[3][0] = fmaf(a4.w, b4.x, acc[3][0]);
      acc[3][1] = fmaf(a4.w, b4.y, acc[3][1]);
      acc[3][2] = fmaf(a4.w, b4.z, acc[3][2]);
      acc[3][3] = fmaf(a4.w, b4.w, acc[3][3]);
    }
    __syncthreads();
  }
}

// fp32 merge (k <= 256). step1: P[q][p] = sum_{l<=q} Tt[b0+q][b0+l] S[a0+p][b0+l]
__global__ __launch_bounds__(256)
void tmerge1_kernel(const float* __restrict__ Tt, const float* __restrict__ S,
                    float* __restrict__ Scv, int k) {
  const int tpk = k >> 6;
  const int tiles = tpk * tpk;
  const int m = blockIdx.x / tiles;
  const int rest = blockIdx.x % tiles;
  const int mb = (rest / tpk) * 64;
  const int nb = (rest % tpk) * 64;
  const int a0 = 2 * k * m, b0 = a0 + k;
  float acc[4][4] = {};
  core64(Tt + (size_t)(b0 + mb) * NT + b0, NT,
         S + (size_t)(a0 + nb) * NT + b0, NT, mb + 64, acc);   // tri-skip
  const int tn = threadIdx.x & 15, tm = threadIdx.x >> 4;
#pragma unroll
  for (int i = 0; i < 4; ++i)
#pragma unroll
    for (int jj = 0; jj < 4; ++jj)
      Scv[(size_t)(1024 + mb + tm * 4 + i) * NT + (size_t)m * k + nb + tn * 4 + jj] = acc[i][jj];
}

// step2: Tt[b0+q][a0+r] = T[a0+r][b0+q] = -sum_{p>=r} P[q][p] T[a0+r][a0+p]
__global__ __launch_bounds__(256)
void tmerge2_kernel(const float* __restrict__ Scv, float* __restrict__ T,
                    float* __restrict__ Tt, int k) {
  const int tpk = k >> 6;
  const int tiles = tpk * tpk;
  const int m = blockIdx.x / tiles;
  const int rest = blockIdx.x % tiles;
  const int mb = (rest / tpk) * 64;
  const int nb = (rest % tpk) * 64;
  const int a0 = 2 * k * m, b0 = a0 + k;
  float acc[4][4] = {};
  core64(Scv + (size_t)(1024 + mb) * NT + (size_t)m * k + nb, NT,
         T + (size_t)(a0 + nb) * NT + a0 + nb, NT, k - nb, acc);   // tri-skip
  const int tn = threadIdx.x & 15, tm = threadIdx.x >> 4;
#pragma unroll
  for (int i = 0; i < 4; ++i) {
    const int q = mb + tm * 4 + i;
#pragma unroll
    for (int jj = 0; jj < 4; ++jj) {
      const int r = nb + tn * 4 + jj;
      const float v = -acc[i][jj];
      Tt[(size_t)(b0 + q) * NT + a0 + r] = v;
      T[(size_t)(a0 + r) * NT + b0 + q] = v;
    }
  }
}

// MFMA merge step1, split-K (SK=2), tri-skip. P0/P1 bases include row offset.
__global__ __launch_bounds__(256)
void tmerge1m_sk(const float* __restrict__ Tt, const float* __restrict__ S,
                 float* __restrict__ P0, float* __restrict__ P1, int k) {
  const int tpk = k >> 7;
  const int tiles = tpk * tpk;
  const int per = tiles * 2;
  const int m = blockIdx.x / per;
  int rest = blockIdx.x % per;
  const int s = rest / tiles; rest %= tiles;
  const int mb = (rest / tpk) * 128;
  const int nb = (rest % tpk) * 128;
  const int a0 = 2 * k * m, b0 = a0 + k;
  const int kend = mb + 128;                    // tri-skip: l <= q
  const int half = ((kend >> 1) + 31) & ~31;
  const int kb0 = s ? half : 0;
  const int kb1 = s ? kend : half;

  __shared__ ushort_t Ahs[128 * LSTR], Als[128 * LSTR], Bhs[128 * LSTR], Bls[128 * LSTR];
  MFMA_DECLS

  for (int kb = kb0; kb < kb1; kb += 32) {
    __syncthreads();
    stage_f32ld(Tt + (size_t)b0 * NT + b0, mb, kb, t, NT, Ahs, Als);
    stage_f32ld(S + (size_t)a0 * NT + b0, nb, kb, t, NT, Bhs, Bls);
    __syncthreads();
    MFMA_BLOCK(Ahs, Als, Bhs, Bls)
  }

  float* outp = s ? P1 : P0;
#pragma unroll
  for (int fm = 0; fm < 4; ++fm) {
    const int m0 = mb + wm * 64 + fm * 16 + lk * 4;
#pragma unroll
    for (int fn = 0; fn < 4; ++fn) {
      const int n = nb + wn * 64 + fn * 16 + lrow;
#pragma unroll
      for (int r = 0; r < 4; ++r)
        outp[(size_t)(m0 + r) * NT + (size_t)m * k + n] = acc[fm][fn][r];
    }
  }
}

// MFMA step2 (k=512): direct, A = P0+P1, tri-skip
__global__ __launch_bounds__(256)
void tmerge2m_full(const float* __restrict__ P0, const float* __restrict__ P1,
                   float* __restrict__ T, float* __restrict__ Tt, int k) {
  const int tpk = k >> 7;
  const int tiles = tpk * tpk;
  const int m = blockIdx.x / tiles;
  const int rest = blockIdx.x % tiles;
  const int mb = (rest / tpk) * 128;
  const int nb = (rest % tpk) * 128;
  const int a0 = 2 * k * m, b0 = a0 + k;

  __shared__ ushort_t Ahs[128 * LSTR], Als[128 * LSTR], Bhs[128 * LSTR], Bls[128 * LSTR];
  MFMA_DECLS

  for (int kb = nb; kb < k; kb += 32) {         // tri-skip: p >= r
    __syncthreads();
    stage_a2(P0 + (size_t)m * k, P1 + (size_t)m * k, mb, kb, t, NT, Ahs, Als);
    stage_f32ld(T + (size_t)a0 * NT + a0, nb, kb, t, NT, Bhs, Bls);
    __syncthreads();
    MFMA_BLOCK(Ahs, Als, Bhs, Bls)
  }

#pragma unroll
  for (int fm = 0; fm < 4; ++fm) {
    const int q0 = mb + wm * 64 + fm * 16 + lk * 4;
#pragma unroll
    for (int fn = 0; fn < 4; ++fn) {
      const int r = nb + wn * 64 + fn * 16 + lrow;
#pragma unroll
      for (int e = 0; e < 4; ++e) {
        const float v = -acc[fm][fn][e];
        Tt[(size_t)(b0 + q0 + e) * NT + a0 + r] = v;
        T[(size_t)(a0 + r) * NT + b0 + q0 + e] = v;
      }
    }
  }
}

// MFMA step2 (k=1024): split-K partials (un-negated) into Pq
__global__ __launch_bounds__(256)
void tmerge2m_sk(const float* __restrict__ P0, const float* __restrict__ P1,
                 const float* __restrict__ T, float* __restrict__ Pq, int k) {
  const int tpk = k >> 7;
  const int tiles = tpk * tpk;
  int rest = blockIdx.x % (tiles * 2);
  const int s = rest / tiles; rest %= tiles;
  const int tile = rest;
  const int mb = (rest / tpk) * 128;
  const int nb = (rest % tpk) * 128;
  const int len = k - nb;                       // tri-skip
  const int half = ((len >> 1) + 31) & ~31;
  const int kb0 = nb + (s ? half : 0);
  const int kb1 = s ? k : nb + half;

  __shared__ ushort_t Ahs[128 * LSTR], Als[128 * LSTR], Bhs[128 * LSTR], Bls[128 * LSTR];
  MFMA_DECLS

  for (int kb = kb0; kb < kb1; kb += 32) {
    __syncthreads();
    stage_a2(P0, P1, mb, kb, t, NT, Ahs, Als);
    stage_f32ld(T, nb, kb, t, NT, Bhs, Bls);    // a0 = 0 at k=1024
    __syncthreads();
    MFMA_BLOCK(Ahs, Als, Bhs, Bls)
  }

  float* outp = Pq + (size_t)(tile * 2 + s) * 16384;
#pragma unroll
  for (int fm = 0; fm < 4; ++fm) {
    const int rl = wm * 64 + fm * 16 + lk * 4;
#pragma unroll
    for (int fn = 0; fn < 4; ++fn) {
      const int cl = wn * 64 + fn * 16 + lrow;
#pragma unroll
      for (int r = 0; r < 4; ++r)
        outp[(rl + r) * 128 + cl] = acc[fm][fn][r];
    }
  }
}

__global__ __launch_bounds__(256)
void t2reduce_kernel(const float* __restrict__ Pq, float* __restrict__ T,
                     float* __restrict__ Tt) {
  const size_t idx4 = ((size_t)blockIdx.x * 256 + threadIdx.x) * 4;
  const int tile = (int)(idx4 >> 14);
  const int off = (int)(idx4 & 16383);
  const int ti2 = tile / 8, tj2 = tile % 8;     // q-block, r-block (tpk=8)
  const int q = ti2 * 128 + off / 128;
  const int r = tj2 * 128 + (off & 127);
  const float* p = Pq + (size_t)tile * 2 * 16384 + off;
  const float4 a = *(const float4*)p;
  const float4 b2 = *(const float4*)(p + 16384);
  float4 v;
  v.x = -(a.x + b2.x); v.y = -(a.y + b2.y);
  v.z = -(a.z + b2.z); v.w = -(a.w + b2.w);
  *(float4*)(Tt + (size_t)(1024 + q) * NT + r) = v;
}

// =================== wbuild: split-K partials + reduce/split ===================

__global__ __launch_bounds__(256)
void wbuild_sk(const ushort_t* __restrict__ UMh, const ushort_t* __restrict__ UMl,
               const float* __restrict__ Tt, float* __restrict__ Pw) {
  const int b = blockIdx.x;
  int tile, s;
  if (b < 256) { tile = b; s = 0; }
  else { const int bb = b - 256; tile = ((bb / 9) + 7) * 16 + (bb % 9) + 7; s = 1; }
  const int ti = tile >> 4, tj = tile & 15;
  const int mb = ti * 128, nb = tj * 128;       // mb = c, nb = j
  const int kend = ((mb < nb ? mb : nb)) + 128; // l <= min(c,j)
  const int big = (ti >= 7 && tj >= 7);
  const int half = big ? (kend >> 1) : kend;    // kend/2 is 64-aligned
  const int kb0 = s ? half : 0;
  const int kb1 = s ? kend : half;

  __shared__ ushort_t Ahs[128 * LSTR], Als[128 * LSTR], Bhs[128 * LSTR], Bls[128 * LSTR];
  MFMA_DECLS

  for (int kb = kb0; kb < kb1; kb += 32) {
    __syncthreads();
    stage_umT(UMh, UMl, mb, kb, t, Ahs, Als);
    stage_f32ld(Tt, nb, kb, t, NT, Bhs, Bls);
    __syncthreads();
    MFMA_BLOCK(Ahs, Als, Bhs, Bls)
  }

  float* outp = Pw + (size_t)b * 16384;
#pragma unroll
  for (int fm = 0; fm < 4; ++fm) {
    const int rl = wm * 64 + fm * 16 + lk * 4;
#pragma unroll
    for (int fn = 0; fn < 4; ++fn) {
      const int cl = wn * 64 + fn * 16 + lrow;
#pragma unroll
      for (int r = 0; r < 4; ++r)
        outp[(rl + r) * 128 + cl] = acc[fm][fn][r];
    }
  }
}

__global__ __launch_bounds__(256)
void wreduce_kernel(const float* __restrict__ Pw,
                    ushort_t* __restrict__ Wh, ushort_t* __restrict__ Wl) {
  const size_t idx4 = ((size_t)blockIdx.x * 256 + threadIdx.x) * 4;
  const int tile = (int)(idx4 >> 14);
  const int off = (int)(idx4 & 16383);
  const int ti = tile >> 4, tj = tile & 15;
  float4 a = *(const float4*)(Pw + (size_t)tile * 16384 + off);
  if (ti >= 7 && tj >= 7) {
    const int slot = 256 + (ti - 7) * 9 + (tj - 7);
    const float4 b2 = *(const float4*)(Pw + (size_t)slot * 16384 + off);
    a.x += b2.x; a.y += b2.y; a.z += b2.z; a.w += b2.w;
  }
  const float f[4] = {a.x, a.y, a.z, a.w};
  ushort_t h[4], l[4];
#pragma unroll
  for (int e = 0; e < 4; ++e) {
    h[e] = f2bf_rtne(f[e]);
    l[e] = f2bf_rtne(f[e] - bf2f(h[e]));
  }
  const size_t o = (size_t)(ti * 128 + off / 128) * NT + tj * 128 + (off & 127);
  *(uint2*)(Wh + o) = make_uint2((unsigned)h[0] | ((unsigned)h[1] << 16),
                                 (unsigned)h[2] | ((unsigned)h[3] << 16));
  *(uint2*)(Wl + o) = make_uint2((unsigned)l[0] | ((unsigned)l[1] << 16),
                                 (unsigned)l[2] | ((unsigned)l[3] << 16));
}

// =================== application GEMMs (pre-split operands) ===================

// EP: 1 = Cf = X - acc ;  2 = write Ch/Cl = bf16split(acc).
template <int EP>
__global__ __launch_bounds__(256)
void gemm_bf_kernel(const ushort_t* __restrict__ Ahg, const ushort_t* __restrict__ Alg,
                    const ushort_t* __restrict__ Bhg, const ushort_t* __restrict__ Blg,
                    const float* __restrict__ X, float* __restrict__ Cf,
                    ushort_t* __restrict__ Ch, ushort_t* __restrict__ Cl,
                    int tri) {
  __shared__ ushort_t Ahs[128 * LSTR], Als[128 * LSTR], Bhs[128 * LSTR], Bls[128 * LSTR];
  int bid = blockIdx.x;
  const int nwg = gridDim.x;
  if ((nwg & 7) == 0) {
    const int q = nwg >> 3;
    bid = (bid & 7) * q + (bid >> 3);
  }
  const int mb = (bid / NT128) * 128;
  const int nb = (bid % NT128) * 128;
  const int k0 = tri ? nb : 0;

  MFMA_DECLS

  for (int kb = k0; kb < NT; kb += 32) {
    __syncthreads();
    stage_pre(Ahg, Alg, mb, kb, t, Ahs, Als);
    stage_pre(Bhg, Blg, nb, kb, t, Bhs, Bls);
    __syncthreads();
    MFMA_BLOCK(Ahs, Als, Bhs, Bls)
  }

#pragma unroll
  for (int fm = 0; fm < 4; ++fm) {
    const int m0 = mb + wm * 64 + fm * 16 + lk * 4;
#pragma unroll
    for (int fn = 0; fn < 4; ++fn) {
      const int n = nb + wn * 64 + fn * 16 + lrow;
#pragma unroll
      for (int r = 0; r < 4; ++r) {
        const size_t idx = (size_t)(m0 + r) * NT + n;
        const float f = acc[fm][fn][r];
        if (EP == 1) {
          Cf[idx] = X[idx] - f;
        } else {
          const ushort_t h = f2bf_rtne(f);
          Ch[idx] = h;
          Cl[idx] = f2bf_rtne(f - bf2f(h));
        }
      }
    }
  }
}

// =================== fallback sweep (round-2, proven) ===================

#define NRF 32
#define VCF 2
#define KGF 8
#define WPBF 4
#define NGRAMF ((KGF * (KGF + 1)) / 2)
#define NREDF (NGRAMF + KGF * VCF)

__device__ __forceinline__ void accum_group_f(const float (&u)[KGF],
                                              const float (&hr)[VCF],
                                              float (&red)[NREDF]) {
#pragma unroll
  for (int j = 0; j < KGF; ++j) {
#pragma unroll
    for (int l = 0; l <= j; ++l)
      red[(j * (j + 1)) / 2 + l] = fmaf(u[j], u[l], red[(j * (j + 1)) / 2 + l]);
#pragma unroll
    for (int c = 0; c < VCF; ++c)
      red[NGRAMF + j * VCF + c] = fmaf(u[j], hr[c], red[NGRAMF + j * VCF + c]);
  }
}

__global__ __launch_bounds__(256, 2)
void fallback_sweep_kernel(const float* __restrict__ x,
                           const float* __restrict__ w,
                           float* __restrict__ out) {
  const int lane = threadIdx.x & 63;
  const int wave = threadIdx.x >> 6;
  const int gw = blockIdx.x * WPBF + wave;
  const int col0 = gw * VCF;
  float h[NRF][VCF];
#pragma unroll
  for (int k = 0; k < NRF; ++k) {
    const int r = lane + 64 * k;
#pragma unroll
    for (int c = 0; c < VCF; ++c) h[k][c] = x[(size_t)(col0 + c) * NT + r];
  }
  for (int i0 = NT - KGF; i0 >= 0; i0 -= KGF) {
    const int ks = i0 >> 6;
    const float* wb = w + (size_t)i0 * NT;
    float red[NREDF];
#pragma unroll
    for (int t = 0; t < NREDF; ++t) red[t] = 0.f;
#pragma unroll
    for (int k = 0; k < NRF; ++k) {
      const int r = lane + 64 * k;
      if (k > ks) {
        float u[KGF];
#pragma unroll
        for (int j = 0; j < KGF; ++j) u[j] = wb[(size_t)j * NT + r];
        accum_group_f(u, h[k], red);
      } else if (k == ks) {
        float u[KGF];
#pragma unroll
        for (int j = 0; j < KGF; ++j) {
          float tt = wb[(size_t)j * NT + r];
          u[j] = (r >= i0 + j) ? tt : 0.f;
        }
        if (i0 == NT - KGF && r == NT - 1) u[KGF - 1] = 1.0f;
        accum_group_f(u, h[k], red);
      }
    }
#pragma unroll
    for (int m = 1; m < 64; m <<= 1)
#pragma unroll
      for (int t = 0; t < NREDF; ++t) red[t] += __shfl_xor(red[t], m, 64);
    float beta[KGF];
#pragma unroll
    for (int j = 0; j < KGF; ++j) {
      const float n2 = red[(j * (j + 1)) / 2 + j];
      beta[j] = (n2 > 0.f) ? 2.0f / n2 : 0.f;
    }
    float T[KGF][KGF];
#pragma unroll
    for (int j = 0; j < KGF; ++j) {
      T[j][j] = beta[j];
#pragma unroll
      for (int r0 = 0; r0 < j; ++r0) {
        float acc = 0.f;
#pragma unroll
        for (int l = r0; l < j; ++l)
          acc = fmaf(T[r0][l], red[(j * (j + 1)) / 2 + l], acc);
        T[r0][j] = -beta[j] * acc;
      }
    }
    float z[KGF][VCF];
#pragma unroll
    for (int j = 0; j < KGF; ++j)
#pragma unroll
      for (int c = 0; c < VCF; ++c) {
        float acc = 0.f;
#pragma unroll
        for (int l = j; l < KGF; ++l)
          acc = fmaf(T[j][l], red[NGRAMF + l * VCF + c], acc);
        z[j][c] = acc;
      }
#pragma unroll
    for (int k = 0; k < NRF; ++k) {
      const int r = lane + 64 * k;
      if (k >= ks) {
        float u[KGF];
#pragma unroll
        for (int j = 0; j < KGF; ++j) {
          float tt = wb[(size_t)j * NT + r];
          u[j] = (k > ks || r >= i0 + j) ? tt : 0.f;
        }
        if (i0 == NT - KGF && r == NT - 1) u[KGF - 1] = 1.0f;
#pragma unroll
        for (int c = 0; c < VCF; ++c) {
          float acc = h[k][c];
#pragma unroll
          for (int j = 0; j < KGF; ++j) acc = fmaf(-u[j], z[j][c], acc);
          h[k][c] = acc;
        }
      }
    }
  }
#pragma unroll
  for (int k = 0; k < NRF; ++k) {
    const int r = lane + 64 * k;
#pragma unroll
    for (int c = 0; c < VCF; ++c)
      out[(size_t)(col0 + c) * NT + r] = h[k][c];
  }
}

// =================== launch ===================

extern "C" void kernel_launch(void* const* d_in, const int* in_sizes, int n_in,
                              void* d_out, int out_size, void* d_ws, size_t ws_size,
                              hipStream_t stream) {
  const float* x = (const float*)d_in[0];
  const float* w = (const float*)d_in[1];
  float* out = (float*)d_out;
  const int Bsz = in_sizes[0] / NT;         // 4096

  const size_t NW = (size_t)NT * NT;        // 4M floats
  float* ws = (float*)d_ws;

  float* S  = ws;
  float* T  = ws + NW;
  float* Tt = ws + 2 * NW;
  ushort_t* UMh = (ushort_t*)(ws + 3 * NW);
  ushort_t* UMl = UMh + NW;
  ushort_t* Wh = (ushort_t*)ws;             // after ladder (S dead)
  ushort_t* Wl = (ushort_t*)(ws + NW / 2);
  ushort_t* A1h = (ushort_t*)(ws + NW);     // after wbuild (T dead)
  ushort_t* A1l = (ushort_t*)(ws + 2 * NW); // after wbuild (Tt dead)
  float* scratch = (float*)d_out;           // staged scratch (dead before out)
  ushort_t* Xh = (ushort_t*)d_out;          // after wreduce
  ushort_t* Xl = Xh + (size_t)Bsz * NT;

  const size_t need = 4 * NW * sizeof(float);   // 64 MB

  if (ws_size < need || (Bsz % 128) != 0 || out_size < (int)(2 * NW)) {
    fallback_sweep_kernel<<<Bsz / (VCF * WPBF), 256, 0, stream>>>(x, w, out);
    return;
  }

  prep_split_kernel<<<(int)(NW / 1024), 256, 0, stream>>>(w, UMh, UMl);

  gram_sk_kernel<<<136 * 3, 256, 0, stream>>>(UMh, UMl, scratch);
  greduce_kernel<<<(136 * 16384) / 1024, 256, 0, stream>>>(scratch, S);

  hipMemsetAsync(T, 0, 2 * NW * sizeof(float), stream);
  tbase64_kernel<<<32, 64, 0, stream>>>(S, T, Tt);

  for (int k = 64; k <= 256; k <<= 1) {
    const int mm = NT / (2 * k);
    const int grid = mm * (k >> 6) * (k >> 6);
    tmerge1_kernel<<<grid, 256, 0, stream>>>(Tt, S, S, k);
    tmerge2_kernel<<<grid, 256, 0, stream>>>(S, T, Tt, k);
  }
  {  // k = 512: SK=2 step1 (P slices in S lower-left), direct step2
    const int k = 512, mm = 2, tiles = 16;
    float* P0 = S + (size_t)1024 * NT;
    float* P1 = S + (size_t)1536 * NT;
    tmerge1m_sk<<<mm * tiles * 2, 256, 0, stream>>>(Tt, S, P0, P1, k);
    tmerge2m_full<<<mm * tiles, 256, 0, stream>>>(P0, P1, T, Tt, k);
  }
  {  // k = 1024: SK=2 both steps (P1 in T lower-left; step2 partials in d_out)
    const int k = 1024, tiles = 64;
    float* P0 = S + (size_t)1024 * NT;
    float* P1 = T + (size_t)1024 * NT;
    tmerge1m_sk<<<tiles * 2, 256, 0, stream>>>(Tt, S, P0, P1, k);
    tmerge2m_sk<<<tiles * 2, 256, 0, stream>>>(P0, P1, T, scratch, k);
    t2reduce_kernel<<<(64 * 16384) / 1024, 256, 0, stream>>>(scratch, T, Tt);
  }

  wbuild_sk<<<337, 256, 0, stream>>>(UMh, UMl, Tt, scratch);
  wreduce_kernel<<<(256 * 16384) / 1024, 256, 0, stream>>>(scratch, Wh, Wl);

  prep_x_kernel<<<(int)((size_t)Bsz * NT / 1024), 256, 0, stream>>>(x, Xh, Xl);

  const int grid = (Bsz / 128) * NT128;     // 512
  gemm_bf_kernel<2><<<grid, 256, 0, stream>>>(
      Xh, Xl, UMh, UMl, nullptr, nullptr, A1h, A1l, 1);
  gemm_bf_kernel<1><<<grid, 256, 0, stream>>>(
      A1h, A1l, Wh, Wl, x, out, nullptr, nullptr, 0);
}

// Round 10
// 571.898 us; speedup vs baseline: 1.5018x; 1.0526x over previous
//
#include <hip/hip_runtime.h>

// OrthogonalTransform via gram + T-matrix (compact WY) + fused application.
// out = X Q^T, Q = I - W V^T, W = V T;  Q^T = I - V W^T.
// Precompute Q2t[d][c] = delta_dc - sum_j W[d][j] UM[j][c]  (tri: j <= c),
// then out = X * Q2t^T  -- ONE application GEMM.
//
// ws (floats, 16M = 64 MB):
//   [0,4M)   S (upper tiles; lower-left = P scratch) -> Wh/Wl after ladder
//   [4,8M)   T  (lower-left dead = P1 @k=1024)       -> Q2h/Q2l after ladder
//   [8,12M)  Tt                                      -> q2 partials after wbuild
//   [12,16M) UMh/UMl                                 -> Xh/Xl after q2build
// d_out scratch (before prep_x only): gram partials, t2 partials, wbuild partials.

#define NT 2048
#define NT128 16
#define LSTR 48            // LDS row stride in shorts (96B): 4-way banks

typedef __attribute__((ext_vector_type(8))) short bf16x8;
typedef __attribute__((ext_vector_type(4))) float f32x4;
typedef unsigned short ushort_t;

__device__ __forceinline__ ushort_t f2bf_rtne(float f) {
  unsigned u = __builtin_bit_cast(unsigned, f);
  u += 0x7FFFu + ((u >> 16) & 1u);
  return (ushort_t)(u >> 16);
}
__device__ __forceinline__ float bf2f(ushort_t h) {
  return __builtin_bit_cast(float, (unsigned)h << 16);
}

// =================== prep kernels ===================

__global__ __launch_bounds__(256)
void prep_split_kernel(const float* __restrict__ w,
                       ushort_t* __restrict__ UMh, ushort_t* __restrict__ UMl) {
  const size_t i4 = ((size_t)blockIdx.x * 256 + threadIdx.x) * 4;
  const int j = (int)(i4 >> 11);
  const int c = (int)(i4 & (NT - 1));
  const float4 v = *(const float4*)(w + i4);
  float f[4] = {v.x, v.y, v.z, v.w};
  ushort_t h[4], l[4];
#pragma unroll
  for (int q = 0; q < 4; ++q) {
    const int cc = c + q;
    float val = f[q];
    if (j == NT - 1 && cc == NT - 1) val = 1.0f;
    val = (cc >= j) ? val : 0.f;
    h[q] = f2bf_rtne(val);
    l[q] = f2bf_rtne(val - bf2f(h[q]));
  }
  *(uint2*)(UMh + i4) = make_uint2((unsigned)h[0] | ((unsigned)h[1] << 16),
                                   (unsigned)h[2] | ((unsigned)h[3] << 16));
  *(uint2*)(UMl + i4) = make_uint2((unsigned)l[0] | ((unsigned)l[1] << 16),
                                   (unsigned)l[2] | ((unsigned)l[3] << 16));
}

__global__ __launch_bounds__(256)
void prep_x_kernel(const float* __restrict__ x,
                   ushort_t* __restrict__ Xh, ushort_t* __restrict__ Xl) {
  const size_t i4 = ((size_t)blockIdx.x * 256 + threadIdx.x) * 4;
  const float4 v = *(const float4*)(x + i4);
  const float f[4] = {v.x, v.y, v.z, v.w};
  ushort_t h[4], l[4];
#pragma unroll
  for (int q = 0; q < 4; ++q) {
    h[q] = f2bf_rtne(f[q]);
    l[q] = f2bf_rtne(f[q] - bf2f(h[q]));
  }
  *(uint2*)(Xh + i4) = make_uint2((unsigned)h[0] | ((unsigned)h[1] << 16),
                                  (unsigned)h[2] | ((unsigned)h[3] << 16));
  *(uint2*)(Xl + i4) = make_uint2((unsigned)l[0] | ((unsigned)l[1] << 16),
                                  (unsigned)l[2] | ((unsigned)l[3] << 16));
}

// =================== MFMA staging (stride LSTR) ===================

__device__ __forceinline__ void stage_f32ld(const float* __restrict__ src,
                                            int rb, int kb, int t, int ld,
                                            ushort_t* __restrict__ Hd,
                                            ushort_t* __restrict__ Ld) {
  const int r0 = t >> 3;
  const int seg = (t & 7) * 4;
#pragma unroll
  for (int p = 0; p < 4; ++p) {
    const int row = r0 + p * 32;
    const float4 v = *(const float4*)(src + (size_t)(rb + row) * ld + kb + seg);
    const float f[4] = {v.x, v.y, v.z, v.w};
    ushort_t h[4], l[4];
#pragma unroll
    for (int q = 0; q < 4; ++q) {
      h[q] = f2bf_rtne(f[q]);
      l[q] = f2bf_rtne(f[q] - bf2f(h[q]));
    }
    const int o = row * LSTR + seg;
    *(uint2*)(Hd + o) = make_uint2((unsigned)h[0] | ((unsigned)h[1] << 16),
                                   (unsigned)h[2] | ((unsigned)h[3] << 16));
    *(uint2*)(Ld + o) = make_uint2((unsigned)l[0] | ((unsigned)l[1] << 16),
                                   (unsigned)l[2] | ((unsigned)l[3] << 16));
  }
}

__device__ __forceinline__ void stage_a2(const float* __restrict__ A0,
                                         const float* __restrict__ A1,
                                         int rb, int kb, int t, int ld,
                                         ushort_t* __restrict__ Hd,
                                         ushort_t* __restrict__ Ld) {
  const int r0 = t >> 3;
  const int seg = (t & 7) * 4;
#pragma unroll
  for (int p = 0; p < 4; ++p) {
    const int row = r0 + p * 32;
    const size_t g = (size_t)(rb + row) * ld + kb + seg;
    const float4 v0 = *(const float4*)(A0 + g);
    const float4 v1 = *(const float4*)(A1 + g);
    const float f[4] = {v0.x + v1.x, v0.y + v1.y, v0.z + v1.z, v0.w + v1.w};
    ushort_t h[4], l[4];
#pragma unroll
    for (int q = 0; q < 4; ++q) {
      h[q] = f2bf_rtne(f[q]);
      l[q] = f2bf_rtne(f[q] - bf2f(h[q]));
    }
    const int o = row * LSTR + seg;
    *(uint2*)(Hd + o) = make_uint2((unsigned)h[0] | ((unsigned)h[1] << 16),
                                   (unsigned)h[2] | ((unsigned)h[3] << 16));
    *(uint2*)(Ld + o) = make_uint2((unsigned)l[0] | ((unsigned)l[1] << 16),
                                   (unsigned)l[2] | ((unsigned)l[3] << 16));
  }
}

__device__ __forceinline__ void stage_pre(const ushort_t* __restrict__ H,
                                          const ushort_t* __restrict__ L,
                                          int rb, int kb, int t,
                                          ushort_t* __restrict__ Hd,
                                          ushort_t* __restrict__ Ld) {
  const int r0 = t >> 1;
  const int seg = (t & 1) << 4;
  const size_t g = (size_t)(rb + r0) * NT + kb + seg;
  const int o = r0 * LSTR + seg;
  *(bf16x8*)(Hd + o) = *(const bf16x8*)(H + g);
  *(bf16x8*)(Hd + o + 8) = *(const bf16x8*)(H + g + 8);
  *(bf16x8*)(Ld + o) = *(const bf16x8*)(L + g);
  *(bf16x8*)(Ld + o + 8) = *(const bf16x8*)(L + g + 8);
}

// UM^T staging: Hd[c][l] = UM[kb+l][cb+c]
__device__ __forceinline__ void stage_umT(const ushort_t* __restrict__ H,
                                          const ushort_t* __restrict__ L,
                                          int cb, int kb, int t,
                                          ushort_t* __restrict__ Hd,
                                          ushort_t* __restrict__ Ld) {
  const int l = t & 31;
  const int grp = t >> 5;
  const size_t g = (size_t)(kb + l) * NT + cb + grp * 16;
  ushort_t hv[16], lv[16];
  *(uint4*)hv = *(const uint4*)(H + g);
  *(uint4*)(hv + 8) = *(const uint4*)(H + g + 8);
  *(uint4*)lv = *(const uint4*)(L + g);
  *(uint4*)(lv + 8) = *(const uint4*)(L + g + 8);
  const int cbl = grp * 16;
#pragma unroll
  for (int e = 0; e < 16; ++e) {
    Hd[(cbl + e) * LSTR + l] = hv[e];
    Ld[(cbl + e) * LSTR + l] = lv[e];
  }
}

#define MFMA_BLOCK(Ahs, Als, Bhs, Bls)                                          \
  {                                                                             \
    bf16x8 ah[4], al[4], bh[4], bl[4];                                          \
    _Pragma("unroll") for (int fm = 0; fm < 4; ++fm) {                          \
      const int o = (wm * 64 + fm * 16 + lrow) * LSTR + lk * 8;                 \
      ah[fm] = *(const bf16x8*)(Ahs + o);                                       \
      al[fm] = *(const bf16x8*)(Als + o);                                       \
    }                                                                           \
    _Pragma("unroll") for (int fn = 0; fn < 4; ++fn) {                          \
      const int o = (wn * 64 + fn * 16 + lrow) * LSTR + lk * 8;                 \
      bh[fn] = *(const bf16x8*)(Bhs + o);                                       \
      bl[fn] = *(const bf16x8*)(Bls + o);                                       \
    }                                                                           \
    _Pragma("unroll") for (int fm = 0; fm < 4; ++fm)                            \
      _Pragma("unroll") for (int fn = 0; fn < 4; ++fn) {                        \
        acc[fm][fn] = __builtin_amdgcn_mfma_f32_16x16x32_bf16(ah[fm], bh[fn], acc[fm][fn], 0, 0, 0); \
        acc[fm][fn] = __builtin_amdgcn_mfma_f32_16x16x32_bf16(ah[fm], bl[fn], acc[fm][fn], 0, 0, 0); \
        acc[fm][fn] = __builtin_amdgcn_mfma_f32_16x16x32_bf16(al[fm], bh[fn], acc[fm][fn], 0, 0, 0); \
      }                                                                         \
  }

#define MFMA_DECLS                                                              \
  const int t = threadIdx.x;                                                    \
  const int l = t & 63, w = t >> 6;                                             \
  const int wm = w >> 1, wn = w & 1;                                            \
  const int lrow = l & 15, lk = l >> 4;                                         \
  f32x4 acc[4][4];                                                              \
  _Pragma("unroll") for (int i = 0; i < 4; ++i)                                 \
    _Pragma("unroll") for (int j = 0; j < 4; ++j) {                             \
      acc[i][j][0] = 0.f; acc[i][j][1] = 0.f;                                   \
      acc[i][j][2] = 0.f; acc[i][j][3] = 0.f;                                   \
    }                                                                           \
  (void)l;

// =================== gram: split-K (SK=3) + reduce ===================

__global__ __launch_bounds__(256)
void gram_sk_kernel(const ushort_t* __restrict__ UMh, const ushort_t* __restrict__ UMl,
                    float* __restrict__ Pg) {
  const int b = blockIdx.x;
  const int tile = b / 3, s = b % 3;
  int rem = tile, ti = 0;
  while (rem >= NT128 - ti) { rem -= NT128 - ti; ++ti; }
  const int tj = ti + rem;
  const int mb = ti * 128, nb = tj * 128;
  const int K = NT - nb;
  const int clen = ((K + 2) / 3 + 31) & ~31;
  int cbeg = nb + s * clen, cend = cbeg + clen;
  if (cbeg > NT) cbeg = NT;
  if (cend > NT) cend = NT;

  __shared__ ushort_t Ahs[128 * LSTR], Als[128 * LSTR], Bhs[128 * LSTR], Bls[128 * LSTR];
  MFMA_DECLS

  for (int kb = cbeg; kb < cend; kb += 32) {
    __syncthreads();
    stage_pre(UMh, UMl, mb, kb, t, Ahs, Als);
    stage_pre(UMh, UMl, nb, kb, t, Bhs, Bls);
    __syncthreads();
    MFMA_BLOCK(Ahs, Als, Bhs, Bls)
  }

  float* outp = Pg + (size_t)b * 16384;
#pragma unroll
  for (int fm = 0; fm < 4; ++fm) {
    const int rl = wm * 64 + fm * 16 + lk * 4;
#pragma unroll
    for (int fn = 0; fn < 4; ++fn) {
      const int cl = wn * 64 + fn * 16 + lrow;
#pragma unroll
      for (int r = 0; r < 4; ++r)
        outp[(rl + r) * 128 + cl] = acc[fm][fn][r];
    }
  }
}

__global__ __launch_bounds__(256)
void greduce_kernel(const float* __restrict__ Pg, float* __restrict__ S) {
  const size_t idx4 = ((size_t)blockIdx.x * 256 + threadIdx.x) * 4;
  const int tile = (int)(idx4 >> 14);
  const int off = (int)(idx4 & 16383);
  int rem = tile, ti = 0;
  while (rem >= NT128 - ti) { rem -= NT128 - ti; ++ti; }
  const int tj = ti + rem;
  const float* p = Pg + (size_t)tile * 3 * 16384 + off;
  float4 a = *(const float4*)p;
  const float4 b2 = *(const float4*)(p + 16384);
  const float4 c2 = *(const float4*)(p + 32768);
  a.x += b2.x + c2.x; a.y += b2.y + c2.y; a.z += b2.z + c2.z; a.w += b2.w + c2.w;
  *(float4*)(S + (size_t)(ti * 128 + off / 128) * NT + tj * 128 + (off & 127)) = a;
}

// =================== tbase64 ===================

__global__ __launch_bounds__(64)
void tbase64_kernel(const float* __restrict__ S, float* __restrict__ T,
                    float* __restrict__ Tt) {
  __shared__ float Tl[64][65];
  __shared__ float Sb[64][65];
  const int g0 = blockIdx.x * 64;
  const int r = threadIdx.x;
  for (int i = 0; i < 64; ++i) Sb[i][r] = S[(size_t)(g0 + i) * NT + g0 + r];
  __syncthreads();

  for (int j = 0; j < 64; ++j) {
    const float sjj = Sb[j][j];
    const float bj = (sjj > 0.f) ? 2.0f / sjj : 0.f;
    float val;
    if (r == j) val = bj;
    else if (r > j) val = 0.f;
    else {
      float a = 0.f;
      for (int ll = r; ll < j; ++ll) a = fmaf(Tl[r][ll], Sb[j][ll], a);
      val = -bj * a;
    }
    Tl[r][j] = val;
    __syncthreads();
  }
  for (int c = 0; c < 64; ++c) T[(size_t)(g0 + r) * NT + g0 + c] = Tl[r][c];
  for (int c = 0; c < 64; ++c) Tt[(size_t)(g0 + c) * NT + g0 + r] = Tl[r][c];
}

// =================== fp32 64x64 NT core ===================

__device__ __forceinline__
void core64(const float* __restrict__ A, int lda,
            const float* __restrict__ B, int ldb,
            int K, float (&acc)[4][4]) {
  __shared__ float As[16][68];
  __shared__ float Bs[16][68];
  const int tid = threadIdx.x;
  const int tn = tid & 15, tm = tid >> 4;
  const int rowl = tid >> 2;
  const int kq = (tid & 3) << 2;

  for (int c = 0; c < K; c += 16) {
    {
      const float4 v = *(const float4*)(A + (size_t)rowl * lda + c + kq);
      As[kq + 0][rowl] = v.x; As[kq + 1][rowl] = v.y;
      As[kq + 2][rowl] = v.z; As[kq + 3][rowl] = v.w;
      const float4 u = *(const float4*)(B + (size_t)rowl * ldb + c + kq);
      Bs[kq + 0][rowl] = u.x; Bs[kq + 1][rowl] = u.y;
      Bs[kq + 2][rowl] = u.z; Bs[kq + 3][rowl] = u.w;
    }
    __syncthreads();
#pragma unroll
    for (int kk = 0; kk < 16; ++kk) {
      const float4 a4 = *(const float4*)&As[kk][tm * 4];
      const float4 b4 = *(const float4*)&Bs[kk][tn * 4];
      acc[0][0] = fmaf(a4.x, b4.x, acc[0][0]);
      acc[0][1] = fmaf(a4.x, b4.y, acc[0][1]);
      acc[0][2] = fmaf(a4.x, b4.z, acc[0][2]);
      acc[0][3] = fmaf(a4.x, b4.w, acc[0][3]);
      acc[1][0] = fmaf(a4.y, b4.x, acc[1][0]);
      acc[1][1] = fmaf(a4.y, b4.y, acc[1][1]);
      acc[1][2] = fmaf(a4.y, b4.z, acc[1][2]);
      acc[1][3] = fmaf(a4.y, b4.w, acc[1][3]);
      acc[2][0] = fmaf(a4.z, b4.x, acc[2][0]);
      acc[2][1] = fmaf(a4.z, b4.y, acc[2][1]);
      acc[2][2] = fmaf(a4.z, b4.z, acc[2][2]);
      acc[2][3] = fmaf(a4.z, b4.w, acc[2][3]);
      acc[3][0] = fmaf(a4.w, b4.x, acc[3][0]);
      acc[3][1] = fmaf(a4.w, b4.y, acc[3][1]);
      acc[3][2] = fmaf(a4.w, b4.z, acc[3][2]);
      acc[3][3] = fmaf(a4.w, b4.w, acc[3][3]);
    }
    __syncthreads();
  }
}

// fp32 merge (k <= 256)
__global__ __launch_bounds__(256)
void tmerge1_kernel(const float* __restrict__ Tt, const float* __restrict__ S,
                    float* __restrict__ Scv, int k) {
  const int tpk = k >> 6;
  const int tiles = tpk * tpk;
  const int m = blockIdx.x / tiles;
  const int rest = blockIdx.x % tiles;
  const int mb = (rest / tpk) * 64;
  const int nb = (rest % tpk) * 64;
  const int a0 = 2 * k * m, b0 = a0 + k;
  float acc[4][4] = {};
  core64(Tt + (size_t)(b0 + mb) * NT + b0, NT,
         S + (size_t)(a0 + nb) * NT + b0, NT, mb + 64, acc);
  const int tn = threadIdx.x & 15, tm = threadIdx.x >> 4;
#pragma unroll
  for (int i = 0; i < 4; ++i)
#pragma unroll
    for (int jj = 0; jj < 4; ++jj)
      Scv[(size_t)(1024 + mb + tm * 4 + i) * NT + (size_t)m * k + nb + tn * 4 + jj] = acc[i][jj];
}

__global__ __launch_bounds__(256)
void tmerge2_kernel(const float* __restrict__ Scv, float* __restrict__ T,
                    float* __restrict__ Tt, int k) {
  const int tpk = k >> 6;
  const int tiles = tpk * tpk;
  const int m = blockIdx.x / tiles;
  const int rest = blockIdx.x % tiles;
  const int mb = (rest / tpk) * 64;
  const int nb = (rest % tpk) * 64;
  const int a0 = 2 * k * m, b0 = a0 + k;
  float acc[4][4] = {};
  core64(Scv + (size_t)(1024 + mb) * NT + (size_t)m * k + nb, NT,
         T + (size_t)(a0 + nb) * NT + a0 + nb, NT, k - nb, acc);
  const int tn = threadIdx.x & 15, tm = threadIdx.x >> 4;
#pragma unroll
  for (int i = 0; i < 4; ++i) {
    const int q = mb + tm * 4 + i;
#pragma unroll
    for (int jj = 0; jj < 4; ++jj) {
      const int r = nb + tn * 4 + jj;
      const float v = -acc[i][jj];
      Tt[(size_t)(b0 + q) * NT + a0 + r] = v;
      T[(size_t)(a0 + r) * NT + b0 + q] = v;
    }
  }
}

// MFMA merge step1, split-K (SK=2), tri-skip
__global__ __launch_bounds__(256)
void tmerge1m_sk(const float* __restrict__ Tt, const float* __restrict__ S,
                 float* __restrict__ P0, float* __restrict__ P1, int k) {
  const int tpk = k >> 7;
  const int tiles = tpk * tpk;
  const int per = tiles * 2;
  const int m = blockIdx.x / per;
  int rest = blockIdx.x % per;
  const int s = rest / tiles; rest %= tiles;
  const int mb = (rest / tpk) * 128;
  const int nb = (rest % tpk) * 128;
  const int a0 = 2 * k * m, b0 = a0 + k;
  const int kend = mb + 128;
  const int half = ((kend >> 1) + 31) & ~31;
  const int kb0 = s ? half : 0;
  const int kb1 = s ? kend : half;

  __shared__ ushort_t Ahs[128 * LSTR], Als[128 * LSTR], Bhs[128 * LSTR], Bls[128 * LSTR];
  MFMA_DECLS

  for (int kb = kb0; kb < kb1; kb += 32) {
    __syncthreads();
    stage_f32ld(Tt + (size_t)b0 * NT + b0, mb, kb, t, NT, Ahs, Als);
    stage_f32ld(S + (size_t)a0 * NT + b0, nb, kb, t, NT, Bhs, Bls);
    __syncthreads();
    MFMA_BLOCK(Ahs, Als, Bhs, Bls)
  }

  float* outp = s ? P1 : P0;
#pragma unroll
  for (int fm = 0; fm < 4; ++fm) {
    const int m0 = mb + wm * 64 + fm * 16 + lk * 4;
#pragma unroll
    for (int fn = 0; fn < 4; ++fn) {
      const int n = nb + wn * 64 + fn * 16 + lrow;
#pragma unroll
      for (int r = 0; r < 4; ++r)
        outp[(size_t)(m0 + r) * NT + (size_t)m * k + n] = acc[fm][fn][r];
    }
  }
}

__global__ __launch_bounds__(256)
void tmerge2m_full(const float* __restrict__ P0, const float* __restrict__ P1,
                   float* __restrict__ T, float* __restrict__ Tt, int k) {
  const int tpk = k >> 7;
  const int tiles = tpk * tpk;
  const int m = blockIdx.x / tiles;
  const int rest = blockIdx.x % tiles;
  const int mb = (rest / tpk) * 128;
  const int nb = (rest % tpk) * 128;
  const int a0 = 2 * k * m, b0 = a0 + k;

  __shared__ ushort_t Ahs[128 * LSTR], Als[128 * LSTR], Bhs[128 * LSTR], Bls[128 * LSTR];
  MFMA_DECLS

  for (int kb = nb; kb < k; kb += 32) {
    __syncthreads();
    stage_a2(P0 + (size_t)m * k, P1 + (size_t)m * k, mb, kb, t, NT, Ahs, Als);
    stage_f32ld(T + (size_t)a0 * NT + a0, nb, kb, t, NT, Bhs, Bls);
    __syncthreads();
    MFMA_BLOCK(Ahs, Als, Bhs, Bls)
  }

#pragma unroll
  for (int fm = 0; fm < 4; ++fm) {
    const int q0 = mb + wm * 64 + fm * 16 + lk * 4;
#pragma unroll
    for (int fn = 0; fn < 4; ++fn) {
      const int r = nb + wn * 64 + fn * 16 + lrow;
#pragma unroll
      for (int e = 0; e < 4; ++e) {
        const float v = -acc[fm][fn][e];
        Tt[(size_t)(b0 + q0 + e) * NT + a0 + r] = v;
        T[(size_t)(a0 + r) * NT + b0 + q0 + e] = v;
      }
    }
  }
}

__global__ __launch_bounds__(256)
void tmerge2m_sk(const float* __restrict__ P0, const float* __restrict__ P1,
                 const float* __restrict__ T, float* __restrict__ Pq, int k) {
  const int tpk = k >> 7;
  const int tiles = tpk * tpk;
  int rest = blockIdx.x % (tiles * 2);
  const int s = rest / tiles; rest %= tiles;
  const int tile = rest;
  const int mb = (rest / tpk) * 128;
  const int nb = (rest % tpk) * 128;
  const int len = k - nb;
  const int half = ((len >> 1) + 31) & ~31;
  const int kb0 = nb + (s ? half : 0);
  const int kb1 = s ? k : nb + half;

  __shared__ ushort_t Ahs[128 * LSTR], Als[128 * LSTR], Bhs[128 * LSTR], Bls[128 * LSTR];
  MFMA_DECLS

  for (int kb = kb0; kb < kb1; kb += 32) {
    __syncthreads();
    stage_a2(P0, P1, mb, kb, t, NT, Ahs, Als);
    stage_f32ld(T, nb, kb, t, NT, Bhs, Bls);
    __syncthreads();
    MFMA_BLOCK(Ahs, Als, Bhs, Bls)
  }

  float* outp = Pq + (size_t)(tile * 2 + s) * 16384;
#pragma unroll
  for (int fm = 0; fm < 4; ++fm) {
    const int rl = wm * 64 + fm * 16 + lk * 4;
#pragma unroll
    for (int fn = 0; fn < 4; ++fn) {
      const int cl = wn * 64 + fn * 16 + lrow;
#pragma unroll
      for (int r = 0; r < 4; ++r)
        outp[(rl + r) * 128 + cl] = acc[fm][fn][r];
    }
  }
}

__global__ __launch_bounds__(256)
void t2reduce_kernel(const float* __restrict__ Pq, float* __restrict__ T,
                     float* __restrict__ Tt) {
  const size_t idx4 = ((size_t)blockIdx.x * 256 + threadIdx.x) * 4;
  const int tile = (int)(idx4 >> 14);
  const int off = (int)(idx4 & 16383);
  const int ti2 = tile / 8, tj2 = tile % 8;
  const int q = ti2 * 128 + off / 128;
  const int r = tj2 * 128 + (off & 127);
  const float* p = Pq + (size_t)tile * 2 * 16384 + off;
  const float4 a = *(const float4*)p;
  const float4 b2 = *(const float4*)(p + 16384);
  float4 v;
  v.x = -(a.x + b2.x); v.y = -(a.y + b2.y);
  v.z = -(a.z + b2.z); v.w = -(a.w + b2.w);
  *(float4*)(Tt + (size_t)(1024 + q) * NT + r) = v;
}

// =================== wbuild: split-K partials + reduce/split ===================

__global__ __launch_bounds__(256)
void wbuild_sk(const ushort_t* __restrict__ UMh, const ushort_t* __restrict__ UMl,
               const float* __restrict__ Tt, float* __restrict__ Pw) {
  const int b = blockIdx.x;
  int tile, s;
  if (b < 256) { tile = b; s = 0; }
  else { const int bb = b - 256; tile = ((bb / 9) + 7) * 16 + (bb % 9) + 7; s = 1; }
  const int ti = tile >> 4, tj = tile & 15;
  const int mb = ti * 128, nb = tj * 128;
  const int kend = ((mb < nb ? mb : nb)) + 128;
  const int big = (ti >= 7 && tj >= 7);
  const int half = big ? (kend >> 1) : kend;
  const int kb0 = s ? half : 0;
  const int kb1 = s ? kend : half;

  __shared__ ushort_t Ahs[128 * LSTR], Als[128 * LSTR], Bhs[128 * LSTR], Bls[128 * LSTR];
  MFMA_DECLS

  for (int kb = kb0; kb < kb1; kb += 32) {
    __syncthreads();
    stage_umT(UMh, UMl, mb, kb, t, Ahs, Als);
    stage_f32ld(Tt, nb, kb, t, NT, Bhs, Bls);
    __syncthreads();
    MFMA_BLOCK(Ahs, Als, Bhs, Bls)
  }

  float* outp = Pw + (size_t)b * 16384;
#pragma unroll
  for (int fm = 0; fm < 4; ++fm) {
    const int rl = wm * 64 + fm * 16 + lk * 4;
#pragma unroll
    for (int fn = 0; fn < 4; ++fn) {
      const int cl = wn * 64 + fn * 16 + lrow;
#pragma unroll
      for (int r = 0; r < 4; ++r)
        outp[(rl + r) * 128 + cl] = acc[fm][fn][r];
    }
  }
}

__global__ __launch_bounds__(256)
void wreduce_kernel(const float* __restrict__ Pw,
                    ushort_t* __restrict__ Wh, ushort_t* __restrict__ Wl) {
  const size_t idx4 = ((size_t)blockIdx.x * 256 + threadIdx.x) * 4;
  const int tile = (int)(idx4 >> 14);
  const int off = (int)(idx4 & 16383);
  const int ti = tile >> 4, tj = tile & 15;
  float4 a = *(const float4*)(Pw + (size_t)tile * 16384 + off);
  if (ti >= 7 && tj >= 7) {
    const int slot = 256 + (ti - 7) * 9 + (tj - 7);
    const float4 b2 = *(const float4*)(Pw + (size_t)slot * 16384 + off);
    a.x += b2.x; a.y += b2.y; a.z += b2.z; a.w += b2.w;
  }
  const float f[4] = {a.x, a.y, a.z, a.w};
  ushort_t h[4], l[4];
#pragma unroll
  for (int e = 0; e < 4; ++e) {
    h[e] = f2bf_rtne(f[e]);
    l[e] = f2bf_rtne(f[e] - bf2f(h[e]));
  }
  const size_t o = (size_t)(ti * 128 + off / 128) * NT + tj * 128 + (off & 127);
  *(uint2*)(Wh + o) = make_uint2((unsigned)h[0] | ((unsigned)h[1] << 16),
                                 (unsigned)h[2] | ((unsigned)h[3] << 16));
  *(uint2*)(Wl + o) = make_uint2((unsigned)l[0] | ((unsigned)l[1] << 16),
                                 (unsigned)l[2] | ((unsigned)l[3] << 16));
}

// =================== q2build: Q2t[d][c] = delta - sum_j W[d][j] UM[j][c] ===================
// Split-K (SK=2) on column-tiles nb_t >= 8; partials (un-negated acc) to Pp.

__global__ __launch_bounds__(256)
void q2build_sk(const ushort_t* __restrict__ Wh, const ushort_t* __restrict__ Wl,
                const ushort_t* __restrict__ UMh, const ushort_t* __restrict__ UMl,
                ushort_t* __restrict__ Q2h, ushort_t* __restrict__ Q2l,
                float* __restrict__ Pp) {
  const int b = blockIdx.x;
  int ti, nb_t, s;
  if (b < 256) { ti = b >> 4; nb_t = b & 15; s = 0; }
  else { const int bb = b - 256; ti = bb >> 3; nb_t = 8 + (bb & 7); s = 1; }
  const int mb = ti * 128, nb = nb_t * 128;
  const int kend = nb + 128;                    // tri: j <= c
  const int split = (nb_t >= 8);
  const int half = split ? (kend >> 1) : kend;  // 64-aligned
  const int kb0 = s ? half : 0;
  const int kb1 = s ? kend : half;

  __shared__ ushort_t Ahs[128 * LSTR], Als[128 * LSTR], Bhs[128 * LSTR], Bls[128 * LSTR];
  MFMA_DECLS

  for (int kb = kb0; kb < kb1; kb += 32) {
    __syncthreads();
    stage_pre(Wh, Wl, mb, kb, t, Ahs, Als);     // A rows = W[d][:]
    stage_umT(UMh, UMl, nb, kb, t, Bhs, Bls);   // B rows = UM^T[c][:]
    __syncthreads();
    MFMA_BLOCK(Ahs, Als, Bhs, Bls)
  }

  if (!split) {
#pragma unroll
    for (int fm = 0; fm < 4; ++fm) {
      const int d0 = mb + wm * 64 + fm * 16 + lk * 4;
#pragma unroll
      for (int fn = 0; fn < 4; ++fn) {
        const int c = nb + wn * 64 + fn * 16 + lrow;
#pragma unroll
        for (int r = 0; r < 4; ++r) {
          const int d = d0 + r;
          const float f = ((d == c) ? 1.0f : 0.0f) - acc[fm][fn][r];
          const size_t idx = (size_t)d * NT + c;
          const ushort_t h = f2bf_rtne(f);
          Q2h[idx] = h;
          Q2l[idx] = f2bf_rtne(f - bf2f(h));
        }
      }
    }
  } else {
    float* outp = Pp + (size_t)((ti * 8 + (nb_t - 8)) * 2 + s) * 16384;
#pragma unroll
    for (int fm = 0; fm < 4; ++fm) {
      const int rl = wm * 64 + fm * 16 + lk * 4;
#pragma unroll
      for (int fn = 0; fn < 4; ++fn) {
        const int cl = wn * 64 + fn * 16 + lrow;
#pragma unroll
        for (int r = 0; r < 4; ++r)
          outp[(rl + r) * 128 + cl] = acc[fm][fn][r];
      }
    }
  }
}

__global__ __launch_bounds__(256)
void q2reduce_kernel(const float* __restrict__ Pp,
                     ushort_t* __restrict__ Q2h, ushort_t* __restrict__ Q2l) {
  const size_t idx4 = ((size_t)blockIdx.x * 256 + threadIdx.x) * 4;
  const int tile = (int)(idx4 >> 14);           // 0..127: ti*8 + (nb_t-8)
  const int off = (int)(idx4 & 16383);
  const int ti = tile >> 3, nbb = tile & 7;
  const float* p = Pp + (size_t)tile * 2 * 16384 + off;
  const float4 a = *(const float4*)p;
  const float4 b2 = *(const float4*)(p + 16384);
  const int d = ti * 128 + off / 128;
  const int c0 = (8 + nbb) * 128 + (off & 127);
  const float sum[4] = {a.x + b2.x, a.y + b2.y, a.z + b2.z, a.w + b2.w};
  ushort_t h[4], l[4];
#pragma unroll
  for (int e = 0; e < 4; ++e) {
    const float f = ((d == c0 + e) ? 1.0f : 0.0f) - sum[e];
    h[e] = f2bf_rtne(f);
    l[e] = f2bf_rtne(f - bf2f(h[e]));
  }
  const size_t o = (size_t)d * NT + c0;
  *(uint2*)(Q2h + o) = make_uint2((unsigned)h[0] | ((unsigned)h[1] << 16),
                                  (unsigned)h[2] | ((unsigned)h[3] << 16));
  *(uint2*)(Q2l + o) = make_uint2((unsigned)l[0] | ((unsigned)l[1] << 16),
                                  (unsigned)l[2] | ((unsigned)l[3] << 16));
}

// =================== application GEMM: out = X * Q2t^T ===================

__global__ __launch_bounds__(256)
void gemm_app_kernel(const ushort_t* __restrict__ Xh, const ushort_t* __restrict__ Xl,
                     const ushort_t* __restrict__ Q2h, const ushort_t* __restrict__ Q2l,
                     float* __restrict__ Cf) {
  __shared__ ushort_t Ahs[128 * LSTR], Als[128 * LSTR], Bhs[128 * LSTR], Bls[128 * LSTR];
  int bid = blockIdx.x;
  const int nwg = gridDim.x;
  if ((nwg & 7) == 0) {
    const int q = nwg >> 3;
    bid = (bid & 7) * q + (bid >> 3);
  }
  const int mb = (bid / NT128) * 128;
  const int nb = (bid % NT128) * 128;

  MFMA_DECLS

  for (int kb = 0; kb < NT; kb += 32) {
    __syncthreads();
    stage_pre(Xh, Xl, mb, kb, t, Ahs, Als);
    stage_pre(Q2h, Q2l, nb, kb, t, Bhs, Bls);
    __syncthreads();
    MFMA_BLOCK(Ahs, Als, Bhs, Bls)
  }

#pragma unroll
  for (int fm = 0; fm < 4; ++fm) {
    const int m0 = mb + wm * 64 + fm * 16 + lk * 4;
#pragma unroll
    for (int fn = 0; fn < 4; ++fn) {
      const int n = nb + wn * 64 + fn * 16 + lrow;
#pragma unroll
      for (int r = 0; r < 4; ++r)
        Cf[(size_t)(m0 + r) * NT + n] = acc[fm][fn][r];
    }
  }
}

// =================== fallback sweep (round-2, proven) ===================

#define NRF 32
#define VCF 2
#define KGF 8
#define WPBF 4
#define NGRAMF ((KGF * (KGF + 1)) / 2)
#define NREDF (NGRAMF + KGF * VCF)

__device__ __forceinline__ void accum_group_f(const float (&u)[KGF],
                                              const float (&hr)[VCF],
                                              float (&red)[NREDF]) {
#pragma unroll
  for (int j = 0; j < KGF; ++j) {
#pragma unroll
    for (int l = 0; l <= j; ++l)
      red[(j * (j + 1)) / 2 + l] = fmaf(u[j], u[l], red[(j * (j + 1)) / 2 + l]);
#pragma unroll
    for (int c = 0; c < VCF; ++c)
      red[NGRAMF + j * VCF + c] = fmaf(u[j], hr[c], red[NGRAMF + j * VCF + c]);
  }
}

__global__ __launch_bounds__(256, 2)
void fallback_sweep_kernel(const float* __restrict__ x,
                           const float* __restrict__ w,
                           float* __restrict__ out) {
  const int lane = threadIdx.x & 63;
  const int wave = threadIdx.x >> 6;
  const int gw = blockIdx.x * WPBF + wave;
  const int col0 = gw * VCF;
  float h[NRF][VCF];
#pragma unroll
  for (int k = 0; k < NRF; ++k) {
    const int r = lane + 64 * k;
#pragma unroll
    for (int c = 0; c < VCF; ++c) h[k][c] = x[(size_t)(col0 + c) * NT + r];
  }
  for (int i0 = NT - KGF; i0 >= 0; i0 -= KGF) {
    const int ks = i0 >> 6;
    const float* wb = w + (size_t)i0 * NT;
    float red[NREDF];
#pragma unroll
    for (int t = 0; t < NREDF; ++t) red[t] = 0.f;
#pragma unroll
    for (int k = 0; k < NRF; ++k) {
      const int r = lane + 64 * k;
      if (k > ks) {
        float u[KGF];
#pragma unroll
        for (int j = 0; j < KGF; ++j) u[j] = wb[(size_t)j * NT + r];
        accum_group_f(u, h[k], red);
      } else if (k == ks) {
        float u[KGF];
#pragma unroll
        for (int j = 0; j < KGF; ++j) {
          float tt = wb[(size_t)j * NT + r];
          u[j] = (r >= i0 + j) ? tt : 0.f;
        }
        if (i0 == NT - KGF && r == NT - 1) u[KGF - 1] = 1.0f;
        accum_group_f(u, h[k], red);
      }
    }
#pragma unroll
    for (int m = 1; m < 64; m <<= 1)
#pragma unroll
      for (int t = 0; t < NREDF; ++t) red[t] += __shfl_xor(red[t], m, 64);
    float beta[KGF];
#pragma unroll
    for (int j = 0; j < KGF; ++j) {
      const float n2 = red[(j * (j + 1)) / 2 + j];
      beta[j] = (n2 > 0.f) ? 2.0f / n2 : 0.f;
    }
    float T[KGF][KGF];
#pragma unroll
    for (int j = 0; j < KGF; ++j) {
      T[j][j] = beta[j];
#pragma unroll
      for (int r0 = 0; r0 < j; ++r0) {
        float acc = 0.f;
#pragma unroll
        for (int l = r0; l < j; ++l)
          acc = fmaf(T[r0][l], red[(j * (j + 1)) / 2 + l], acc);
        T[r0][j] = -beta[j] * acc;
      }
    }
    float z[KGF][VCF];
#pragma unroll
    for (int j = 0; j < KGF; ++j)
#pragma unroll
      for (int c = 0; c < VCF; ++c) {
        float acc = 0.f;
#pragma unroll
        for (int l = j; l < KGF; ++l)
          acc = fmaf(T[j][l], red[NGRAMF + l * VCF + c], acc);
        z[j][c] = acc;
      }
#pragma unroll
    for (int k = 0; k < NRF; ++k) {
      const int r = lane + 64 * k;
      if (k >= ks) {
        float u[KGF];
#pragma unroll
        for (int j = 0; j < KGF; ++j) {
          float tt = wb[(size_t)j * NT + r];
          u[j] = (k > ks || r >= i0 + j) ? tt : 0.f;
        }
        if (i0 == NT - KGF && r == NT - 1) u[KGF - 1] = 1.0f;
#pragma unroll
        for (int c = 0; c < VCF; ++c) {
          float acc = h[k][c];
#pragma unroll
          for (int j = 0; j < KGF; ++j) acc = fmaf(-u[j], z[j][c], acc);
          h[k][c] = acc;
        }
      }
    }
  }
#pragma unroll
  for (int k = 0; k < NRF; ++k) {
    const int r = lane + 64 * k;
#pragma unroll
    for (int c = 0; c < VCF; ++c)
      out[(size_t)(col0 + c) * NT + r] = h[k][c];
  }
}

// =================== launch ===================

extern "C" void kernel_launch(void* const* d_in, const int* in_sizes, int n_in,
                              void* d_out, int out_size, void* d_ws, size_t ws_size,
                              hipStream_t stream) {
  const float* x = (const float*)d_in[0];
  const float* w = (const float*)d_in[1];
  float* out = (float*)d_out;
  const int Bsz = in_sizes[0] / NT;         // 4096

  const size_t NW = (size_t)NT * NT;        // 4M floats
  float* ws = (float*)d_ws;

  float* S  = ws;
  float* T  = ws + NW;
  float* Tt = ws + 2 * NW;
  ushort_t* UMh = (ushort_t*)(ws + 3 * NW);
  ushort_t* UMl = UMh + NW;
  ushort_t* Wh = (ushort_t*)ws;             // after ladder (S dead)
  ushort_t* Wl = (ushort_t*)(ws + NW / 2);
  ushort_t* Q2h = (ushort_t*)(ws + NW);     // after ladder (T dead)
  ushort_t* Q2l = (ushort_t*)(ws + 3 * NW / 2);
  float* Pq2 = ws + 2 * NW;                 // q2 partials (Tt dead after wbuild)
  ushort_t* Xh = (ushort_t*)(ws + 3 * NW);  // after q2build (UM dead)
  ushort_t* Xl = Xh + (size_t)Bsz * NT;
  float* scratch = (float*)d_out;           // pre-prep_x scratch only

  const size_t need = 4 * NW * sizeof(float);   // 64 MB

  if (ws_size < need || (Bsz % 128) != 0 || out_size < (int)(2 * NW)) {
    fallback_sweep_kernel<<<Bsz / (VCF * WPBF), 256, 0, stream>>>(x, w, out);
    return;
  }

  prep_split_kernel<<<(int)(NW / 1024), 256, 0, stream>>>(w, UMh, UMl);

  gram_sk_kernel<<<136 * 3, 256, 0, stream>>>(UMh, UMl, scratch);
  greduce_kernel<<<(136 * 16384) / 1024, 256, 0, stream>>>(scratch, S);

  hipMemsetAsync(T, 0, 2 * NW * sizeof(float), stream);
  tbase64_kernel<<<32, 64, 0, stream>>>(S, T, Tt);

  for (int k = 64; k <= 256; k <<= 1) {
    const int mm = NT / (2 * k);
    const int grid = mm * (k >> 6) * (k >> 6);
    tmerge1_kernel<<<grid, 256, 0, stream>>>(Tt, S, S, k);
    tmerge2_kernel<<<grid, 256, 0, stream>>>(S, T, Tt, k);
  }
  {  // k = 512
    const int k = 512, mm = 2, tiles = 16;
    float* P0 = S + (size_t)1024 * NT;
    float* P1 = S + (size_t)1536 * NT;
    tmerge1m_sk<<<mm * tiles * 2, 256, 0, stream>>>(Tt, S, P0, P1, k);
    tmerge2m_full<<<mm * tiles, 256, 0, stream>>>(P0, P1, T, Tt, k);
  }
  {  // k = 1024
    const int k = 1024, tiles = 64;
    float* P0 = S + (size_t)1024 * NT;
    float* P1 = T + (size_t)1024 * NT;
    tmerge1m_sk<<<tiles * 2, 256, 0, stream>>>(Tt, S, P0, P1, k);
    tmerge2m_sk<<<tiles * 2, 256, 0, stream>>>(P0, P1, T, scratch, k);
    t2reduce_kernel<<<(64 * 16384) / 1024, 256, 0, stream>>>(scratch, T, Tt);
  }

  wbuild_sk<<<337, 256, 0, stream>>>(UMh, UMl, Tt, scratch);
  wreduce_kernel<<<(256 * 16384) / 1024, 256, 0, stream>>>(scratch, Wh, Wl);

  // Q2t = I - W V^T  (reads Wh/Wl + UMh/UMl; partials in dead Tt region)
  q2build_sk<<<384, 256, 0, stream>>>(Wh, Wl, UMh, UMl, Q2h, Q2l, Pq2);
  q2reduce_kernel<<<(128 * 16384) / 1024, 256, 0, stream>>>(Pq2, Q2h, Q2l);

  // X -> bf16 pair (UM region now dead)
  prep_x_kernel<<<(int)((size_t)Bsz * NT / 1024), 256, 0, stream>>>(x, Xh, Xl);

  // out = X * Q2t^T  (single application GEMM)
  const int grid = (Bsz / 128) * NT128;     // 512
  gemm_app_kernel<<<grid, 256, 0, stream>>>(Xh, Xl, Q2h, Q2l, out);
}